// Round 2
// baseline (2166.728 us; speedup 1.0000x reference)
//
#include <hip/hip_runtime.h>
#include <hip/hip_bf16.h>
#include <math.h>

// ---------------- problem constants ----------------
#define B_   2
#define G_   8
#define D_   128
#define H_   80
#define W_   160
#define N_   (B_*H_*W_)     // 25600
#define P_   4
#define CTX_ 64
#define C_   128
#define FD_  128
#define NROWS (N_*P_)       // 102400

// output chunk offsets (FLOAT32 elements) — d_out is float* (ref outputs fp32/int32)
#define OUT_CV     ((size_t)0)
#define OUT_PROB   ((size_t)26214400)
#define OUT_SEEDS  ((size_t)29491200)
#define OUT_LABELS ((size_t)29593600)

typedef __attribute__((ext_vector_type(8))) short short8;
typedef __attribute__((ext_vector_type(4))) float float4v;

__device__ __forceinline__ float bf2f(unsigned short u){
  unsigned v = ((unsigned)u) << 16;
  return __builtin_bit_cast(float, v);
}
__device__ __forceinline__ unsigned short f2bf(float f){
  __hip_bfloat16 h = __float2bfloat16(f);   // RNE
  return __builtin_bit_cast(unsigned short, h);
}
__device__ __forceinline__ void load8f(const unsigned short* p, float* f){
  uint4 u = *(const uint4*)p;
  const unsigned short* us = (const unsigned short*)&u;
  #pragma unroll
  for(int i=0;i<8;i++) f[i]=bf2f(us[i]);
}
__device__ __forceinline__ void add_resid32(float* v, const unsigned short* rp){
  #pragma unroll
  for(int i=0;i<4;i++){
    uint4 u = ((const uint4*)rp)[i];
    const unsigned short* us=(const unsigned short*)&u;
    #pragma unroll
    for(int k=0;k<8;k++) v[i*8+k]+=bf2f(us[k]);
  }
}
// per-thread holds 32 cols (segment qq of 4); 4 consecutive lanes = one row
__device__ __forceinline__ void ln_write32(float* v, int colbase, const float* g, const float* b,
                                           unsigned short* dst){
  float s=0.f, sq=0.f;
  #pragma unroll
  for(int i=0;i<32;i++){ s+=v[i]; sq+=v[i]*v[i]; }
  s  += __shfl_xor(s,1);  sq += __shfl_xor(sq,1);
  s  += __shfl_xor(s,2);  sq += __shfl_xor(sq,2);
  float mu  = s*(1.f/128.f);
  float var = sq*(1.f/128.f) - mu*mu;
  float rs  = rsqrtf(var+1e-5f);
  union{unsigned short us[32]; uint4 u4[4];} pk;
  #pragma unroll
  for(int i=0;i<32;i++) pk.us[i]=f2bf((v[i]-mu)*rs*g[colbase+i]+b[colbase+i]);
  uint4* op=(uint4*)dst;
  #pragma unroll
  for(int i=0;i<4;i++) op[i]=pk.u4[i];
}

// ---------------- weight convert+transpose: dst[n*K+k] = bf16(src[k*N+n]) ----------------
__global__ void k_cvtT(const float* __restrict__ src, unsigned short* __restrict__ dst, int K, int N){
  int i = blockIdx.x*256 + threadIdx.x;
  if(i < K*N){
    int n = i / K, k = i % K;
    dst[(size_t)n*K + k] = f2bf(src[(size_t)k*N + n]);
  }
}

// ---------------- cost volume transpose: [B,G,D,H,W] -> cv[N,G,D] fp32 directly in d_out --
__global__ __launch_bounds__(256) void k_transpose(const float* __restrict__ cvol,
                                                   float* __restrict__ outf){
  __shared__ float t[32][33];
  int z = blockIdx.z;                 // bg*H + h ; bg = b*G+g
  int h = z % H_;  int bg = z / H_;
  int w0 = blockIdx.x*32, d0 = blockIdx.y*32;
  int tx = threadIdx.x, ty = threadIdx.y;   // 32 x 8
  #pragma unroll
  for(int i=0;i<4;i++){
    int d = d0 + ty + i*8;
    t[ty+i*8][tx] = cvol[(((size_t)bg*D_ + d)*H_ + h)*W_ + w0 + tx];
  }
  __syncthreads();
  int b = bg / G_, g = bg % G_;
  #pragma unroll
  for(int i=0;i<4;i++){
    int wl = ty + i*8;
    int n = (b*H_+h)*W_ + w0 + wl;
    size_t o = ((size_t)n*G_ + g)*D_ + d0 + tx;
    outf[OUT_CV + o] = t[tx][wl];
  }
}

// ---------------- cost filter (conv1d chain) + softmax + local-max + stable top-4 --------
// reads cv from d_out chunk 0; writes prob (fp32) + seeds (fp32) + seeds_i
__global__ __launch_bounds__(128) void k_cost(
    const float* __restrict__ w1, const float* __restrict__ b1,
    const float* __restrict__ w2, const float* __restrict__ b2,
    const float* __restrict__ w3, const float* __restrict__ b3,
    float* __restrict__ outf, int* __restrict__ seeds_i){
  __shared__ float cvs[G_][D_];
  __shared__ float h1s[8][D_];
  __shared__ float h2s[16][D_];
  __shared__ float ps[D_];
  __shared__ float pv[D_];
  __shared__ float rv[D_];
  __shared__ int   ri[D_];
  __shared__ float red[D_];
  int n = blockIdx.x, d = threadIdx.x;
  const float* cvf = outf + OUT_CV;
  #pragma unroll
  for(int g=0; g<G_; g++) cvs[g][d] = cvf[((size_t)n*G_+g)*D_ + d];
  __syncthreads();
  // conv1: G=8 -> 8, k5 pad2, relu
  float a1[8];
  #pragma unroll
  for(int c=0;c<8;c++) a1[c]=b1[c];
  for(int g=0; g<8; g++)
    #pragma unroll
    for(int j=0;j<5;j++){
      int idx = d + j - 2;
      float v = (idx>=0 && idx<D_) ? cvs[g][idx] : 0.f;
      #pragma unroll
      for(int c=0;c<8;c++) a1[c] += v * w1[(c*8+g)*5 + j];
    }
  #pragma unroll
  for(int c=0;c<8;c++) h1s[c][d]=fmaxf(a1[c],0.f);
  __syncthreads();
  // conv2: 8 -> 16
  float a2[16];
  #pragma unroll
  for(int c=0;c<16;c++) a2[c]=b2[c];
  for(int g=0; g<8; g++)
    #pragma unroll
    for(int j=0;j<5;j++){
      int idx = d + j - 2;
      float v = (idx>=0 && idx<D_) ? h1s[g][idx] : 0.f;
      #pragma unroll
      for(int c=0;c<16;c++) a2[c] += v * w2[(c*8+g)*5 + j];
    }
  #pragma unroll
  for(int c=0;c<16;c++) h2s[c][d]=fmaxf(a2[c],0.f);
  __syncthreads();
  // conv3: 16 -> 1
  float cost=b3[0];
  for(int g=0; g<16; g++)
    #pragma unroll
    for(int j=0;j<5;j++){
      int idx = d + j - 2;
      if(idx>=0 && idx<D_) cost += h2s[g][idx]*w3[g*5+j];
    }
  // softmax (exact expf for seed stability)
  red[d]=cost; __syncthreads();
  for(int s=64;s>0;s>>=1){ if(d<s) red[d]=fmaxf(red[d],red[d+s]); __syncthreads(); }
  float m=red[0]; __syncthreads();
  float e=expf(cost-m);
  red[d]=e; __syncthreads();
  for(int s=64;s>0;s>>=1){ if(d<s) red[d]+=red[d+s]; __syncthreads(); }
  float prob = e/red[0];
  ps[d]=prob;
  outf[OUT_PROB + (size_t)n*D_ + d] = prob;
  __syncthreads();
  float pooled = prob;
  if(d>0)    pooled = fmaxf(pooled, ps[d-1]);
  if(d<127)  pooled = fmaxf(pooled, ps[d+1]);
  bool nlm = (prob != pooled) && (prob > 1e-3f);
  pv[d] = nlm ? 1e-3f : prob;
  __syncthreads();
  for(int p=0;p<P_;p++){
    rv[d]=pv[d]; ri[d]=d; __syncthreads();
    for(int s=64;s>0;s>>=1){
      if(d<s){
        float vb=rv[d+s]; int ib=ri[d+s];
        if(vb>rv[d] || (vb==rv[d] && ib<ri[d])){ rv[d]=vb; ri[d]=ib; }
      }
      __syncthreads();
    }
    if(d==0){
      int sd = ri[0];
      seeds_i[n*P_+p]=sd;
      outf[OUT_SEEDS + (size_t)n*P_ + p]=(float)sd;
      pv[sd] = -1e30f;
    }
    __syncthreads();
  }
}

// ---------------- conv3x3 (128->128, pad1, no bias) ----------------
__global__ __launch_bounds__(256) void k_conv3(const float* __restrict__ fmap,
                                               const float* __restrict__ w,
                                               float* __restrict__ tmp3){
  __shared__ float in_t[8][10][10];
  int w0 = blockIdx.x*8, h0 = blockIdx.y*8;
  int z = blockIdx.z; int b = z >> 3; int co0 = (z & 7)*16;
  int t = threadIdx.x;
  int s = t & 63, sx = s & 7, sy = s >> 3, gq = t >> 6;   // gq wave-uniform
  float acc[4] = {0.f,0.f,0.f,0.f};
  for(int c0=0;c0<128;c0+=8){
    __syncthreads();
    for(int idx=t; idx<800; idx+=256){
      int c = idx/100, r=(idx%100)/10, cc=idx%10;
      int gh=h0-1+r, gw=w0-1+cc;
      float v=0.f;
      if(gh>=0 && gh<H_ && gw>=0 && gw<W_)
        v = fmap[(((size_t)b*FD_+c0+c)*H_+gh)*W_+gw];
      in_t[c][r][cc]=v;
    }
    __syncthreads();
    #pragma unroll
    for(int c=0;c<8;c++)
      #pragma unroll
      for(int ky=0;ky<3;ky++)
        #pragma unroll
        for(int kx=0;kx<3;kx++){
          float v = in_t[c][sy+ky][sx+kx];
          #pragma unroll
          for(int j=0;j<4;j++){
            int co = co0 + gq*4 + j;
            acc[j] += v * w[((size_t)co*128 + c0+c)*9 + ky*3+kx];
          }
        }
  }
  #pragma unroll
  for(int j=0;j<4;j++){
    int co = co0+gq*4+j;
    tmp3[(((size_t)b*128+co)*H_+h0+sy)*W_+w0+sx] = acc[j];
  }
}

// ---------------- instance norm stats ----------------
__global__ __launch_bounds__(256) void k_inorm(const float* __restrict__ tmp3,
                                               float* __restrict__ musg){
  int bc = blockIdx.x;
  const float* p = tmp3 + (size_t)bc*H_*W_;
  float s=0.f, sq=0.f;
  for(int i=threadIdx.x;i<H_*W_;i+=256){ float v=p[i]; s+=v; sq+=v*v; }
  __shared__ float rs_[256], rq_[256];
  rs_[threadIdx.x]=s; rq_[threadIdx.x]=sq; __syncthreads();
  for(int st=128;st>0;st>>=1){
    if(threadIdx.x<st){ rs_[threadIdx.x]+=rs_[threadIdx.x+st]; rq_[threadIdx.x]+=rq_[threadIdx.x+st]; }
    __syncthreads();
  }
  if(threadIdx.x==0){
    float mu = rs_[0]/(float)(H_*W_);
    float var = rq_[0]/(float)(H_*W_) - mu*mu;
    musg[bc*2]=mu; musg[bc*2+1]=rsqrtf(var+1e-5f);
  }
}

// ---------------- norm+relu+conv1x1 -> ctxT[64][N] ----------------
__global__ __launch_bounds__(256) void k_ctx(const float* __restrict__ tmp3,
                                             const float* __restrict__ musg,
                                             const float* __restrict__ w2,
                                             float* __restrict__ ctxT){
  __shared__ float nl[128][33];
  int w0 = blockIdx.x*32; int h = blockIdx.y; int b = blockIdx.z;
  int t = threadIdx.x;
  for(int idx=t; idx<128*32; idx+=256){
    int c = idx>>5, wl = idx&31;
    float v = tmp3[(((size_t)b*128+c)*H_+h)*W_+w0+wl];
    v = (v - musg[(b*128+c)*2]) * musg[(b*128+c)*2+1];
    nl[c][wl] = fmaxf(v, 0.f);
  }
  __syncthreads();
  int wl = t & 31, cg = t >> 5;
  float acc[8]={0.f,0.f,0.f,0.f,0.f,0.f,0.f,0.f};
  for(int c=0;c<128;c++){
    float v = nl[c][wl];
    #pragma unroll
    for(int j=0;j<8;j++) acc[j] += v * w2[(size_t)(cg*8+j)*128 + c];
  }
  int n = (b*H_+h)*W_ + w0 + wl;
  #pragma unroll
  for(int j=0;j<8;j++) ctxT[(size_t)(cg*8+j)*N_ + n] = acc[j];
}

// ---------------- seed embedding + ctx projection -> Xb bf16 [NROWS,128] ----------------
__global__ __launch_bounds__(256) void k_embed(const float* __restrict__ outf,
    const float* __restrict__ ctxT, const int* __restrict__ seeds_i,
    const float* __restrict__ embed_w, const float* __restrict__ embed_b,
    const float* __restrict__ ctx_w, const float* __restrict__ ctx_b,
    unsigned short* __restrict__ Xb){
  __shared__ float feats[16][72];
  __shared__ float cvv[4][64];
  const float* cvf = outf + OUT_CV;
  int n0 = blockIdx.x*4;
  int t = threadIdx.x;
  for(int idx=t; idx<16*72; idx+=256){
    int r = idx/72, j = idx%72;
    int n = n0 + (r>>2), p = r&3;
    int sd = seeds_i[n*4+p];
    int g = j/9, tt = j%9;
    int di = sd + tt - 4; di = di<0?0:(di>127?127:di);
    feats[r][j] = cvf[((size_t)n*8+g)*128 + di];
  }
  for(int idx=t; idx<4*64; idx+=256){
    int nl_ = idx>>6, k = idx&63;
    cvv[nl_][k] = ctxT[(size_t)k*N_ + n0+nl_];
  }
  __syncthreads();
  int col = t & 127, rg = t >> 7;
  float acc[8];
  float bb = embed_b[col] + ctx_b[col];
  #pragma unroll
  for(int r=0;r<8;r++) acc[r]=bb;
  for(int j=0;j<72;j++){
    float wv = embed_w[(size_t)j*128+col];
    #pragma unroll
    for(int r=0;r<8;r++) acc[r] += feats[rg*8+r][j]*wv;
  }
  for(int k=0;k<64;k++){
    float wv = ctx_w[(size_t)k*128+col];
    #pragma unroll
    for(int r=0;r<8;r++) acc[r] += cvv[(rg*8+r)>>2][k]*wv;
  }
  #pragma unroll
  for(int r=0;r<8;r++){
    int row = n0*4 + rg*8 + r;
    Xb[(size_t)row*128 + col] = f2bf(acc[r]);
  }
}

// ---------------- qkv GEMM (MFMA) + windowed attention -> Ob bf16 ----------------
__global__ __launch_bounds__(256) void k_qkv_attn(const unsigned short* __restrict__ Xb,
    const unsigned short* __restrict__ qkvT, const float* __restrict__ qkv_b,
    unsigned short* __restrict__ Ob){
  __shared__ __align__(16) unsigned short qb[64][136];
  __shared__ __align__(16) unsigned short kb[64][136];
  __shared__ __align__(16) unsigned short vb[64][136];
  int t = threadIdx.x, lane = t & 63, wv = t >> 6;
  int m = lane & 15, q = lane >> 4;
  int rbase = blockIdx.x*64;
  int row = rbase + wv*16 + m;
  short8 af[4];
  const short8* ap = (const short8*)(Xb + (size_t)row*128);
  #pragma unroll
  for(int kk=0;kk<4;kk++) af[kk] = ap[kk*4+q];
  for(int nt=0; nt<24; nt++){
    int n0 = nt*16;
    float4v acc = {0.f,0.f,0.f,0.f};
    const short8* bp = (const short8*)(qkvT + (size_t)(n0 + m)*128);
    #pragma unroll
    for(int kk=0;kk<4;kk++)
      acc = __builtin_amdgcn_mfma_f32_16x16x32_bf16(af[kk], bp[kk*4+q], acc, 0,0,0);
    int col = n0 + m;
    float bias = qkv_b[col];
    unsigned short* dst = (col<128)? &qb[0][0] : (col<256? &kb[0][0] : &vb[0][0]);
    int cl = col & 127;
    #pragma unroll
    for(int j=0;j<4;j++){
      int rr = wv*16 + q*4 + j;
      dst[rr*136 + cl] = f2bf(acc[j] + bias);
    }
  }
  __syncthreads();
  // attention: thread = (window=t>>6, head=(t>>4)&3, qrow=t&15); all data wave-local
  int win = t >> 6, head = (t>>4)&3, qr = t & 15;
  const float scale = 0.17677669529663687f;  // 1/sqrt(32)
  float qv[32];
  load8f(&qb[win*16+qr][head*32+0],  qv+0);
  load8f(&qb[win*16+qr][head*32+8],  qv+8);
  load8f(&qb[win*16+qr][head*32+16], qv+16);
  load8f(&qb[win*16+qr][head*32+24], qv+24);
  float s[16];
  #pragma unroll
  for(int k=0;k<16;k++){
    float kvv[32];
    load8f(&kb[win*16+k][head*32+0],  kvv+0);
    load8f(&kb[win*16+k][head*32+8],  kvv+8);
    load8f(&kb[win*16+k][head*32+16], kvv+16);
    load8f(&kb[win*16+k][head*32+24], kvv+24);
    float a=0.f;
    #pragma unroll
    for(int d=0;d<32;d++) a += qv[d]*kvv[d];
    s[k]=a*scale;
  }
  float mx=s[0];
  #pragma unroll
  for(int k=1;k<16;k++) mx=fmaxf(mx,s[k]);
  float sum=0.f;
  #pragma unroll
  for(int k=0;k<16;k++){ s[k]=__expf(s[k]-mx); sum+=s[k]; }
  float inv=1.f/sum;
  float o[32];
  #pragma unroll
  for(int d=0;d<32;d++) o[d]=0.f;
  #pragma unroll
  for(int k=0;k<16;k++){
    float p = s[k]*inv;
    float vvv[32];
    load8f(&vb[win*16+k][head*32+0],  vvv+0);
    load8f(&vb[win*16+k][head*32+8],  vvv+8);
    load8f(&vb[win*16+k][head*32+16], vvv+16);
    load8f(&vb[win*16+k][head*32+24], vvv+24);
    #pragma unroll
    for(int d=0;d<32;d++) o[d] += p*vvv[d];
  }
  union{unsigned short us[32]; uint4 u4[4];} pk;
  #pragma unroll
  for(int d=0;d<32;d++) pk.us[d]=f2bf(o[d]);
  uint4* op=(uint4*)(Ob + (size_t)(rbase + win*16 + qr)*128 + head*32);
  #pragma unroll
  for(int i=0;i<4;i++) op[i]=pk.u4[i];
}

// ---------------- generic 128x128 GEMM; MODE 0: bias+relu, MODE 1: bias+resid+LN --------
template<int MODE>
__global__ __launch_bounds__(256) void k_gemm128(const unsigned short* __restrict__ Ab,
    const unsigned short* __restrict__ WT, const float* __restrict__ bias,
    const unsigned short* __restrict__ resid, const float* __restrict__ lng,
    const float* __restrict__ lnb, unsigned short* __restrict__ outb){
  __shared__ float ef[64*132];
  int t=threadIdx.x, lane=t&63, wv=t>>6;
  int m=lane&15, q=lane>>4;
  int rbase=blockIdx.x*64;
  short8 af[4];
  const short8* ap=(const short8*)(Ab + (size_t)(rbase+wv*16+m)*128);
  #pragma unroll
  for(int kk=0;kk<4;kk++) af[kk]=ap[kk*4+q];
  #pragma unroll
  for(int nt=0;nt<8;nt++){
    float4v acc={0.f,0.f,0.f,0.f};
    const short8* bp=(const short8*)(WT + (size_t)(nt*16+m)*128);
    #pragma unroll
    for(int kk=0;kk<4;kk++)
      acc=__builtin_amdgcn_mfma_f32_16x16x32_bf16(af[kk],bp[kk*4+q],acc,0,0,0);
    int col=nt*16+m;
    float bv=bias[col];
    #pragma unroll
    for(int j=0;j<4;j++) ef[(wv*16+q*4+j)*132 + col]=acc[j]+bv;
  }
  __syncthreads();
  int r=t>>2, qq=t&3;
  float v[32];
  const float* er=&ef[r*132+qq*32];
  #pragma unroll
  for(int i=0;i<32;i++) v[i]=er[i];
  size_t gro=(size_t)(rbase+r)*128+qq*32;
  if(MODE==0){
    union{unsigned short us[32]; uint4 u4[4];} pk;
    #pragma unroll
    for(int i=0;i<32;i++) pk.us[i]=f2bf(fmaxf(v[i],0.f));
    uint4* op=(uint4*)(outb+gro);
    #pragma unroll
    for(int i=0;i<4;i++) op[i]=pk.u4[i];
  } else {
    add_resid32(v, resid+gro);
    ln_write32(v, qq*32, lng, lnb, outb+gro);
  }
}

// ---------------- fused MLP: fc1+gelu(LDS) + fc2 + resid + LN2 ----------------
__global__ __launch_bounds__(256) void k_mlp(const unsigned short* __restrict__ X2b,
    const unsigned short* __restrict__ fc1T, const float* __restrict__ fc1b,
    const unsigned short* __restrict__ fc2T, const float* __restrict__ fc2b,
    const float* __restrict__ lng, const float* __restrict__ lnb,
    unsigned short* __restrict__ Xbout){
  __shared__ __align__(16) unsigned short hb[64*512];   // 64 KB, 16B-block xor-swizzled
  int t=threadIdx.x, lane=t&63, wv=t>>6;
  int m=lane&15, q=lane>>4;
  int rbase=blockIdx.x*64;
  short8 af[4];
  const short8* ap=(const short8*)(X2b + (size_t)(rbase+wv*16+m)*128);
  #pragma unroll
  for(int kk=0;kk<4;kk++) af[kk]=ap[kk*4+q];
  // fc1 (N=512) in two halves of 16 col-tiles to bound registers
  for(int half=0; half<2; half++){
    float4v acc[16];
    #pragma unroll
    for(int i=0;i<16;i++) acc[i]=(float4v){0.f,0.f,0.f,0.f};
    #pragma unroll
    for(int nt=0;nt<16;nt++){
      int n0=(half*16+nt)*16;
      const short8* bp=(const short8*)(fc1T + (size_t)(n0+m)*128);
      #pragma unroll
      for(int kk=0;kk<4;kk++)
        acc[nt]=__builtin_amdgcn_mfma_f32_16x16x32_bf16(af[kk],bp[kk*4+q],acc[nt],0,0,0);
    }
    #pragma unroll
    for(int nt=0;nt<16;nt++){
      int col=(half*16+nt)*16+m;
      float bv=fc1b[col];
      int bblk = col>>3;
      #pragma unroll
      for(int j=0;j<4;j++){
        int rr=wv*16+q*4+j;
        float x=acc[nt][j]+bv;
        float gel = 0.5f*x*(1.f+erff(x*0.70710678118654752f));   // exact gelu
        hb[rr*512 + ((bblk ^ (rr&63))<<3) + (col&7)] = f2bf(gel);
      }
    }
  }
  __syncthreads();
  // fc2 (K=512, N=128)
  int arow = wv*16+m;
  short8 haf[16];
  #pragma unroll
  for(int kk=0;kk<16;kk++){
    int bb=kk*4+q;
    haf[kk]=*(const short8*)&hb[arow*512 + ((bb ^ (arow&63))<<3)];
  }
  float4v acc2[8];
  #pragma unroll
  for(int i=0;i<8;i++) acc2[i]=(float4v){0.f,0.f,0.f,0.f};
  #pragma unroll
  for(int nt=0;nt<8;nt++){
    const short8* bp=(const short8*)(fc2T + (size_t)(nt*16+m)*512);
    #pragma unroll
    for(int kk=0;kk<16;kk++)
      acc2[nt]=__builtin_amdgcn_mfma_f32_16x16x32_bf16(haf[kk],bp[kk*4+q],acc2[nt],0,0,0);
  }
  __syncthreads();           // hb reads done -> reuse as f32 epilogue buffer
  float* ef=(float*)hb;      // 64*132 floats = 33.8 KB
  #pragma unroll
  for(int nt=0;nt<8;nt++){
    int col=nt*16+m;
    float bv=fc2b[col];
    #pragma unroll
    for(int j=0;j<4;j++) ef[(wv*16+q*4+j)*132+col]=acc2[nt][j]+bv;
  }
  __syncthreads();
  int r=t>>2, qq=t&3;
  float v[32];
  #pragma unroll
  for(int i=0;i<32;i++) v[i]=ef[r*132+qq*32+i];
  size_t gro=(size_t)(rbase+r)*128+qq*32;
  add_resid32(v, X2b+gro);
  ln_write32(v, qq*32, lng, lnb, Xbout+gro);
}

// ---------------- standalone LN (final norm) ----------------
__global__ __launch_bounds__(256) void k_lnfinal(const unsigned short* __restrict__ Xb,
    const float* __restrict__ g, const float* __restrict__ b,
    unsigned short* __restrict__ Mb){
  int t=threadIdx.x;
  int r=t>>2, qq=t&3;
  size_t gro=(size_t)(blockIdx.x*64+r)*128+qq*32;
  float v[32];
  #pragma unroll
  for(int i=0;i<4;i++){
    uint4 u=((const uint4*)(Xb+gro))[i];
    const unsigned short* us=(const unsigned short*)&u;
    #pragma unroll
    for(int k=0;k<8;k++) v[i*8+k]=bf2f(us[k]);
  }
  ln_write32(v, qq*32, g, b, Mb+gro);
}

// ---------------- head final dot + labels (fp32 out) ----------------
__global__ __launch_bounds__(256) void k_head3(const unsigned short* __restrict__ H2b,
    const float* __restrict__ h3w, const float* __restrict__ h3b,
    const int* __restrict__ seeds_i, float* __restrict__ outf){
  int row=blockIdx.x*256+threadIdx.x;
  const uint4* rp=(const uint4*)(H2b+(size_t)row*128);
  float acc=h3b[0];
  #pragma unroll
  for(int i=0;i<8;i++){
    uint4 u=rp[i];
    const unsigned short* us=(const unsigned short*)&u;
    #pragma unroll
    for(int j=0;j<8;j++) acc += bf2f(us[j])*h3w[i*8+j];
  }
  float lab=fmaxf(acc+(float)seeds_i[row],0.f);
  outf[OUT_LABELS+row]=lab;
}

// ============================================================================
extern "C" void kernel_launch(void* const* d_in, const int* in_sizes, int n_in,
                              void* d_out, int out_size, void* d_ws, size_t ws_size,
                              hipStream_t stream) {
  const float* cost_volume=(const float*)d_in[0];
  const float* fmap1   =(const float*)d_in[1];
  const float* mlp_w1  =(const float*)d_in[2];
  const float* mlp_b1  =(const float*)d_in[3];
  const float* mlp_w2  =(const float*)d_in[4];
  const float* mlp_b2  =(const float*)d_in[5];
  const float* mlp_w3  =(const float*)d_in[6];
  const float* mlp_b3  =(const float*)d_in[7];
  const float* proj_w1 =(const float*)d_in[8];
  const float* proj_w2 =(const float*)d_in[9];
  const float* embed_w =(const float*)d_in[10];
  const float* embed_b =(const float*)d_in[11];
  const float* ctx_w   =(const float*)d_in[12];
  const float* ctx_b   =(const float*)d_in[13];
  const float* ln1_g   =(const float*)d_in[14];
  const float* ln1_b   =(const float*)d_in[15];
  const float* qkv_w   =(const float*)d_in[16];
  const float* qkv_b   =(const float*)d_in[17];
  const float* attn_w  =(const float*)d_in[18];
  const float* attn_b  =(const float*)d_in[19];
  const float* ln2_g   =(const float*)d_in[20];
  const float* ln2_b   =(const float*)d_in[21];
  const float* fc1_w   =(const float*)d_in[22];
  const float* fc1_b   =(const float*)d_in[23];
  const float* fc2_w   =(const float*)d_in[24];
  const float* fc2_b   =(const float*)d_in[25];
  const float* normf_g =(const float*)d_in[26];
  const float* normf_b =(const float*)d_in[27];
  const float* h1_w    =(const float*)d_in[28];
  const float* h1_b    =(const float*)d_in[29];
  const float* h2_w    =(const float*)d_in[30];
  const float* h2_b    =(const float*)d_in[31];
  const float* h3_w    =(const float*)d_in[32];
  const float* h3_b    =(const float*)d_in[33];
  float* outf = (float*)d_out;        // fp32 output: cv | prob | seeds | labels

  // workspace layout (bytes, 256-aligned)
  char* ws=(char*)d_ws;
  unsigned short* act    =(unsigned short*)(ws + 0);             // 104,857,600 B (Ob|Mb|H1b|H2b)
  float*          tmp3   =(float*)(ws + 104857600);              //  13,107,200 B
  float*          musg   =(float*)(ws + 117964800);              //       2,048 B
  float*          ctxT   =(float*)(ws + 117966848);              //   6,553,600 B
  int*            seeds_i=(int*)  (ws + 124520448);              //     409,600 B
  unsigned short* Xb     =(unsigned short*)(ws + 124930048);     //  26,214,400 B
  unsigned short* X2b    =(unsigned short*)(ws + 151144448);     //  26,214,400 B
  unsigned short* wbf    =(unsigned short*)(ws + 177358848);     //     851,968 B
  const size_t NEEDED = 178210816;
  if (ws_size < NEEDED) return;
  unsigned short* Ob  = act;
  unsigned short* Mb  = Ob  + 13107200;
  unsigned short* H1b = Mb  + 13107200;
  unsigned short* H2b = H1b + 13107200;
  // bf16 transposed weights
  unsigned short* qkvT = wbf;             // 2 x [384][128]
  unsigned short* attnT= wbf + 98304;     // 2 x [128][128]
  unsigned short* fc1T = wbf + 131072;    // 2 x [512][128]
  unsigned short* fc2T = wbf + 262144;    // 2 x [128][512]
  unsigned short* h1T  = wbf + 393216;
  unsigned short* h2T  = wbf + 409600;

  // weight conversion (independent of data path)
  k_cvtT<<<192,256,0,stream>>>(qkv_w,        qkvT,        128,384);
  k_cvtT<<<192,256,0,stream>>>(qkv_w+49152,  qkvT+49152,  128,384);
  k_cvtT<<<64, 256,0,stream>>>(attn_w,       attnT,       128,128);
  k_cvtT<<<64, 256,0,stream>>>(attn_w+16384, attnT+16384, 128,128);
  k_cvtT<<<256,256,0,stream>>>(fc1_w,        fc1T,        128,512);
  k_cvtT<<<256,256,0,stream>>>(fc1_w+65536,  fc1T+65536,  128,512);
  k_cvtT<<<256,256,0,stream>>>(fc2_w,        fc2T,        512,128);
  k_cvtT<<<256,256,0,stream>>>(fc2_w+65536,  fc2T+65536,  512,128);
  k_cvtT<<<64, 256,0,stream>>>(h1_w,         h1T,         128,128);
  k_cvtT<<<64, 256,0,stream>>>(h2_w,         h2T,         128,128);

  // stage 1: transpose (cv -> d_out chunk 0, fp32) + cost filter + seeds
  k_transpose<<<dim3(5,4,1280), dim3(32,8), 0, stream>>>(cost_volume, outf);
  k_cost<<<N_,128,0,stream>>>(mlp_w1,mlp_b1, mlp_w2,mlp_b2, mlp_w3,mlp_b3, outf, seeds_i);

  // stage 2: context projection
  k_conv3<<<dim3(20,10,16),256,0,stream>>>(fmap1, proj_w1, tmp3);
  k_inorm<<<256,256,0,stream>>>(tmp3, musg);
  k_ctx<<<dim3(5,80,2),256,0,stream>>>(tmp3, musg, proj_w2, ctxT);

  // stage 3: embedding
  k_embed<<<6400,256,0,stream>>>(outf, ctxT, seeds_i, embed_w, embed_b, ctx_w, ctx_b, Xb);

  // stage 4: transformer (2 layers)
  for(int l=0;l<2;l++){
    k_qkv_attn<<<1600,256,0,stream>>>(Xb, qkvT + (size_t)l*49152, qkv_b + l*384, Ob);
    k_gemm128<1><<<1600,256,0,stream>>>(Ob, attnT + (size_t)l*16384, attn_b + l*128,
                                        Xb, ln1_g + l*128, ln1_b + l*128, X2b);
    k_mlp<<<1600,256,0,stream>>>(X2b, fc1T + (size_t)l*65536, fc1_b + l*512,
                                 fc2T + (size_t)l*65536, fc2_b + l*128,
                                 ln2_g + l*128, ln2_b + l*128, Xb);
  }

  // stage 5: final norm + head
  k_lnfinal<<<1600,256,0,stream>>>(Xb, normf_g, normf_b, Mb);
  k_gemm128<0><<<1600,256,0,stream>>>(Mb,  h1T, h1_b, nullptr, nullptr, nullptr, H1b);
  k_gemm128<0><<<1600,256,0,stream>>>(H1b, h2T, h2_b, nullptr, nullptr, nullptr, H2b);
  k_head3<<<400,256,0,stream>>>(H2b, h3_w, h3_b, seeds_i, outf);
}

// Round 3
// 1750.018 us; speedup vs baseline: 1.2381x; 1.2381x over previous
//
#include <hip/hip_runtime.h>
#include <hip/hip_bf16.h>
#include <math.h>

// ---------------- problem constants ----------------
#define B_   2
#define G_   8
#define D_   128
#define H_   80
#define W_   160
#define N_   (B_*H_*W_)     // 25600
#define P_   4
#define CTX_ 64
#define C_   128
#define FD_  128
#define NROWS (N_*P_)       // 102400

// output chunk offsets (FLOAT32 elements) — d_out is float* (ref outputs fp32/int32)
#define OUT_CV     ((size_t)0)
#define OUT_PROB   ((size_t)26214400)
#define OUT_SEEDS  ((size_t)29491200)
#define OUT_LABELS ((size_t)29593600)

typedef __attribute__((ext_vector_type(8))) short short8;
typedef __attribute__((ext_vector_type(4))) float float4v;

__device__ __forceinline__ float bf2f(unsigned short u){
  unsigned v = ((unsigned)u) << 16;
  return __builtin_bit_cast(float, v);
}
__device__ __forceinline__ unsigned short f2bf(float f){
  __hip_bfloat16 h = __float2bfloat16(f);   // RNE
  return __builtin_bit_cast(unsigned short, h);
}
__device__ __forceinline__ void load8f(const unsigned short* p, float* f){
  uint4 u = *(const uint4*)p;
  const unsigned short* us = (const unsigned short*)&u;
  #pragma unroll
  for(int i=0;i<8;i++) f[i]=bf2f(us[i]);
}
__device__ __forceinline__ void add_resid32(float* v, const unsigned short* rp){
  #pragma unroll
  for(int i=0;i<4;i++){
    uint4 u = ((const uint4*)rp)[i];
    const unsigned short* us=(const unsigned short*)&u;
    #pragma unroll
    for(int k=0;k<8;k++) v[i*8+k]+=bf2f(us[k]);
  }
}
// per-thread holds 32 cols (segment qq of 4); 4 consecutive lanes = one row
__device__ __forceinline__ void ln_write32(float* v, int colbase, const float* g, const float* b,
                                           unsigned short* dst){
  float s=0.f, sq=0.f;
  #pragma unroll
  for(int i=0;i<32;i++){ s+=v[i]; sq+=v[i]*v[i]; }
  s  += __shfl_xor(s,1);  sq += __shfl_xor(sq,1);
  s  += __shfl_xor(s,2);  sq += __shfl_xor(sq,2);
  float mu  = s*(1.f/128.f);
  float var = sq*(1.f/128.f) - mu*mu;
  float rs  = rsqrtf(var+1e-5f);
  union{unsigned short us[32]; uint4 u4[4];} pk;
  #pragma unroll
  for(int i=0;i<32;i++) pk.us[i]=f2bf((v[i]-mu)*rs*g[colbase+i]+b[colbase+i]);
  uint4* op=(uint4*)dst;
  #pragma unroll
  for(int i=0;i<4;i++) op[i]=pk.u4[i];
}

// ---------------- merged weight convert+transpose (10 segments in 1 launch) -------------
// dst[r] = bf16(src[(r & (K-1))*N + (r>>ks)])   with K = 1<<ks   (dst[n*K+k] = src[k*N+n])
struct CvtSeg { const float* src; unsigned short* dst; int ks; int N; int base; };
struct CvtArgs { CvtSeg s[10]; };
__global__ __launch_bounds__(256) void k_cvt_all(CvtArgs a, int grand_total){
  int i = blockIdx.x*256 + threadIdx.x;
  if(i >= grand_total) return;
  int seg = 0;
  #pragma unroll
  for(int s=1;s<10;s++) if(i >= a.s[s].base) seg = s;
  int r = i - a.s[seg].base;
  int ks = a.s[seg].ks;
  int k = r & ((1<<ks)-1);
  int n = r >> ks;
  a.s[seg].dst[r] = f2bf(a.s[seg].src[(size_t)k*a.s[seg].N + n]);
}

// ---------------- conv3 weight reorder: BT[co][tap*128+ci] = w[co][ci][tap] bf16 ---------
__global__ __launch_bounds__(256) void k_cvtW3(const float* __restrict__ w,
                                               unsigned short* __restrict__ BT){
  int i = blockIdx.x*256 + threadIdx.x;
  if(i < 128*1152){
    int co = i / 1152, rem = i % 1152;
    int tap = rem >> 7, ci = rem & 127;
    BT[i] = f2bf(w[((size_t)co*128 + ci)*9 + tap]);
  }
}

// ---------------- fmap transpose: [B,128,H,W] f32 -> fT [B,H,W,128] bf16 ----------------
__global__ __launch_bounds__(256) void k_fmapT(const float* __restrict__ fmap,
                                               unsigned short* __restrict__ fT){
  __shared__ float t[32][33];
  int w0 = blockIdx.x*32, c0 = blockIdx.y*32;
  int z = blockIdx.z; int b = z / H_; int h = z % H_;
  int tx = threadIdx.x, ty = threadIdx.y;   // 32 x 8
  #pragma unroll
  for(int i=0;i<4;i++){
    int c = c0 + ty + i*8;
    t[ty+i*8][tx] = fmap[(((size_t)b*FD_ + c)*H_ + h)*W_ + w0 + tx];
  }
  __syncthreads();
  #pragma unroll
  for(int i=0;i<4;i++){
    int wl = ty + i*8;
    fT[(((size_t)b*H_ + h)*W_ + w0 + wl)*128 + c0 + tx] = f2bf(t[tx][wl]);
  }
}

// ---------------- cost volume transpose: [B,G,D,H,W] -> cv[N,G,D] fp32 directly in d_out --
__global__ __launch_bounds__(256) void k_transpose(const float* __restrict__ cvol,
                                                   float* __restrict__ outf){
  __shared__ float t[32][33];
  int z = blockIdx.z;                 // bg*H + h ; bg = b*G+g
  int h = z % H_;  int bg = z / H_;
  int w0 = blockIdx.x*32, d0 = blockIdx.y*32;
  int tx = threadIdx.x, ty = threadIdx.y;   // 32 x 8
  #pragma unroll
  for(int i=0;i<4;i++){
    int d = d0 + ty + i*8;
    t[ty+i*8][tx] = cvol[(((size_t)bg*D_ + d)*H_ + h)*W_ + w0 + tx];
  }
  __syncthreads();
  int b = bg / G_, g = bg % G_;
  #pragma unroll
  for(int i=0;i<4;i++){
    int wl = ty + i*8;
    int n = (b*H_+h)*W_ + w0 + wl;
    size_t o = ((size_t)n*G_ + g)*D_ + d0 + tx;
    outf[OUT_CV + o] = t[tx][wl];
  }
}

// ---------------- cost filter (conv1d chain) + softmax + local-max + stable top-4 --------
// reads cv from d_out chunk 0; writes prob (fp32) + seeds (fp32) + seeds_i
__global__ __launch_bounds__(128) void k_cost(
    const float* __restrict__ w1, const float* __restrict__ b1,
    const float* __restrict__ w2, const float* __restrict__ b2,
    const float* __restrict__ w3, const float* __restrict__ b3,
    float* __restrict__ outf, int* __restrict__ seeds_i){
  __shared__ float cvs[G_][D_];
  __shared__ float h1s[8][D_];
  __shared__ float h2s[16][D_];
  __shared__ float ps[D_];
  __shared__ float pv[D_];
  __shared__ float rv[D_];
  __shared__ int   ri[D_];
  __shared__ float red[D_];
  int n = blockIdx.x, d = threadIdx.x;
  const float* cvf = outf + OUT_CV;
  #pragma unroll
  for(int g=0; g<G_; g++) cvs[g][d] = cvf[((size_t)n*G_+g)*D_ + d];
  __syncthreads();
  // conv1: G=8 -> 8, k5 pad2, relu
  float a1[8];
  #pragma unroll
  for(int c=0;c<8;c++) a1[c]=b1[c];
  for(int g=0; g<8; g++)
    #pragma unroll
    for(int j=0;j<5;j++){
      int idx = d + j - 2;
      float v = (idx>=0 && idx<D_) ? cvs[g][idx] : 0.f;
      #pragma unroll
      for(int c=0;c<8;c++) a1[c] += v * w1[(c*8+g)*5 + j];
    }
  #pragma unroll
  for(int c=0;c<8;c++) h1s[c][d]=fmaxf(a1[c],0.f);
  __syncthreads();
  // conv2: 8 -> 16
  float a2[16];
  #pragma unroll
  for(int c=0;c<16;c++) a2[c]=b2[c];
  for(int g=0; g<8; g++)
    #pragma unroll
    for(int j=0;j<5;j++){
      int idx = d + j - 2;
      float v = (idx>=0 && idx<D_) ? h1s[g][idx] : 0.f;
      #pragma unroll
      for(int c=0;c<16;c++) a2[c] += v * w2[(c*8+g)*5 + j];
    }
  #pragma unroll
  for(int c=0;c<16;c++) h2s[c][d]=fmaxf(a2[c],0.f);
  __syncthreads();
  // conv3: 16 -> 1
  float cost=b3[0];
  for(int g=0; g<16; g++)
    #pragma unroll
    for(int j=0;j<5;j++){
      int idx = d + j - 2;
      if(idx>=0 && idx<D_) cost += h2s[g][idx]*w3[g*5+j];
    }
  // softmax (exact expf for seed stability)
  red[d]=cost; __syncthreads();
  for(int s=64;s>0;s>>=1){ if(d<s) red[d]=fmaxf(red[d],red[d+s]); __syncthreads(); }
  float m=red[0]; __syncthreads();
  float e=expf(cost-m);
  red[d]=e; __syncthreads();
  for(int s=64;s>0;s>>=1){ if(d<s) red[d]+=red[d+s]; __syncthreads(); }
  float prob = e/red[0];
  ps[d]=prob;
  outf[OUT_PROB + (size_t)n*D_ + d] = prob;
  __syncthreads();
  float pooled = prob;
  if(d>0)    pooled = fmaxf(pooled, ps[d-1]);
  if(d<127)  pooled = fmaxf(pooled, ps[d+1]);
  bool nlm = (prob != pooled) && (prob > 1e-3f);
  pv[d] = nlm ? 1e-3f : prob;
  __syncthreads();
  for(int p=0;p<P_;p++){
    rv[d]=pv[d]; ri[d]=d; __syncthreads();
    for(int s=64;s>0;s>>=1){
      if(d<s){
        float vb=rv[d+s]; int ib=ri[d+s];
        if(vb>rv[d] || (vb==rv[d] && ib<ri[d])){ rv[d]=vb; ri[d]=ib; }
      }
      __syncthreads();
    }
    if(d==0){
      int sd = ri[0];
      seeds_i[n*P_+p]=sd;
      outf[OUT_SEEDS + (size_t)n*P_ + p]=(float)sd;
      pv[sd] = -1e30f;
    }
    __syncthreads();
  }
}

// ---------------- conv3x3 as MFMA im2col GEMM: fT[B,H,W,128]bf16 × BT[128co][1152] ------
// block: 2 h-rows × 32 w × 64 co-half; 4 waves, wave = 16 px (rowt=wv>>1, wcol=(wv&1)*16)
__global__ __launch_bounds__(256) void k_conv3(const unsigned short* __restrict__ fT,
                                               const unsigned short* __restrict__ BT,
                                               float* __restrict__ tmp3){
  __shared__ __align__(16) unsigned short hal[4*34*136];  // [r][w][c], c padded to 136
  int t = threadIdx.x, lane = t & 63, wv = t >> 6;
  int m = lane & 15, q = lane >> 4;
  int w0 = blockIdx.x*32;            // 5
  int h0 = blockIdx.y*2;             // 40
  int bz = blockIdx.z;               // 4: b = bz>>1, co half = bz&1
  int b  = bz >> 1;
  int co0 = (bz & 1)*64;
  // stage halo rows h0-1..h0+2, w w0-1..w0+32, 128 ch (zero-filled OOB)
  for(int idx=t; idx<4*34*16; idx+=256){
    int chunk = idx & 15;            // 8-ch block
    int pos = idx >> 4;              // r*34+wl
    int r = pos / 34, wl = pos % 34;
    int gh = h0 - 1 + r, gw = w0 - 1 + wl;
    uint4 v = {0u,0u,0u,0u};
    if(gh>=0 && gh<H_ && gw>=0 && gw<W_)
      v = *(const uint4*)(fT + ((((size_t)b*H_+gh)*W_+gw)<<7) + chunk*8);
    *(uint4*)&hal[pos*136 + chunk*8] = v;
  }
  __syncthreads();
  int rowt = wv >> 1, wcol = (wv & 1)*16;
  float4v acc[4];
  #pragma unroll
  for(int i=0;i<4;i++) acc[i]=(float4v){0.f,0.f,0.f,0.f};
  #pragma unroll
  for(int ky=0;ky<3;ky++){
    #pragma unroll
    for(int kx=0;kx<3;kx++){
      int tap = ky*3+kx;
      const unsigned short* abase = &hal[((rowt+ky)*34 + wcol + m + kx)*136 + q*8];
      short8 af[4];
      #pragma unroll
      for(int kk=0;kk<4;kk++) af[kk] = *(const short8*)(abase + kk*32);
      #pragma unroll
      for(int nt=0;nt<4;nt++){
        const short8* bp = (const short8*)(BT + (size_t)(co0 + nt*16 + m)*1152 + tap*128);
        #pragma unroll
        for(int kk=0;kk<4;kk++)
          acc[nt] = __builtin_amdgcn_mfma_f32_16x16x32_bf16(af[kk], bp[kk*4+q], acc[nt], 0,0,0);
      }
    }
  }
  int h = h0 + rowt;
  #pragma unroll
  for(int nt=0;nt<4;nt++){
    int co = co0 + nt*16 + m;
    *(float4v*)(tmp3 + (((size_t)b*128+co)*H_ + h)*W_ + w0 + wcol + q*4) = acc[nt];
  }
}

// ---------------- instance norm stats ----------------
__global__ __launch_bounds__(256) void k_inorm(const float* __restrict__ tmp3,
                                               float* __restrict__ musg){
  int bc = blockIdx.x;
  const float* p = tmp3 + (size_t)bc*H_*W_;
  float s=0.f, sq=0.f;
  for(int i=threadIdx.x;i<H_*W_;i+=256){ float v=p[i]; s+=v; sq+=v*v; }
  __shared__ float rs_[256], rq_[256];
  rs_[threadIdx.x]=s; rq_[threadIdx.x]=sq; __syncthreads();
  for(int st=128;st>0;st>>=1){
    if(threadIdx.x<st){ rs_[threadIdx.x]+=rs_[threadIdx.x+st]; rq_[threadIdx.x]+=rq_[threadIdx.x+st]; }
    __syncthreads();
  }
  if(threadIdx.x==0){
    float mu = rs_[0]/(float)(H_*W_);
    float var = rq_[0]/(float)(H_*W_) - mu*mu;
    musg[bc*2]=mu; musg[bc*2+1]=rsqrtf(var+1e-5f);
  }
}

// ---------------- norm+relu+conv1x1 -> ctxT[64][N] ----------------
__global__ __launch_bounds__(256) void k_ctx(const float* __restrict__ tmp3,
                                             const float* __restrict__ musg,
                                             const float* __restrict__ w2,
                                             float* __restrict__ ctxT){
  __shared__ float nl[128][33];
  int w0 = blockIdx.x*32; int h = blockIdx.y; int b = blockIdx.z;
  int t = threadIdx.x;
  for(int idx=t; idx<128*32; idx+=256){
    int c = idx>>5, wl = idx&31;
    float v = tmp3[(((size_t)b*128+c)*H_+h)*W_+w0+wl];
    v = (v - musg[(b*128+c)*2]) * musg[(b*128+c)*2+1];
    nl[c][wl] = fmaxf(v, 0.f);
  }
  __syncthreads();
  int wl = t & 31, cg = t >> 5;
  float acc[8]={0.f,0.f,0.f,0.f,0.f,0.f,0.f,0.f};
  for(int c=0;c<128;c++){
    float v = nl[c][wl];
    #pragma unroll
    for(int j=0;j<8;j++) acc[j] += v * w2[(size_t)(cg*8+j)*128 + c];
  }
  int n = (b*H_+h)*W_ + w0 + wl;
  #pragma unroll
  for(int j=0;j<8;j++) ctxT[(size_t)(cg*8+j)*N_ + n] = acc[j];
}

// ---------------- seed embedding + ctx projection -> Xb bf16 [NROWS,128] ----------------
__global__ __launch_bounds__(256) void k_embed(const float* __restrict__ outf,
    const float* __restrict__ ctxT, const int* __restrict__ seeds_i,
    const float* __restrict__ embed_w, const float* __restrict__ embed_b,
    const float* __restrict__ ctx_w, const float* __restrict__ ctx_b,
    unsigned short* __restrict__ Xb){
  __shared__ float feats[16][72];
  __shared__ float cvv[4][64];
  const float* cvf = outf + OUT_CV;
  int n0 = blockIdx.x*4;
  int t = threadIdx.x;
  for(int idx=t; idx<16*72; idx+=256){
    int r = idx/72, j = idx%72;
    int n = n0 + (r>>2), p = r&3;
    int sd = seeds_i[n*4+p];
    int g = j/9, tt = j%9;
    int di = sd + tt - 4; di = di<0?0:(di>127?127:di);
    feats[r][j] = cvf[((size_t)n*8+g)*128 + di];
  }
  for(int idx=t; idx<4*64; idx+=256){
    int nl_ = idx>>6, k = idx&63;
    cvv[nl_][k] = ctxT[(size_t)k*N_ + n0+nl_];
  }
  __syncthreads();
  int col = t & 127, rg = t >> 7;
  float acc[8];
  float bb = embed_b[col] + ctx_b[col];
  #pragma unroll
  for(int r=0;r<8;r++) acc[r]=bb;
  for(int j=0;j<72;j++){
    float wv = embed_w[(size_t)j*128+col];
    #pragma unroll
    for(int r=0;r<8;r++) acc[r] += feats[rg*8+r][j]*wv;
  }
  for(int k=0;k<64;k++){
    float wv = ctx_w[(size_t)k*128+col];
    #pragma unroll
    for(int r=0;r<8;r++) acc[r] += cvv[(rg*8+r)>>2][k]*wv;
  }
  #pragma unroll
  for(int r=0;r<8;r++){
    int row = n0*4 + rg*8 + r;
    Xb[(size_t)row*128 + col] = f2bf(acc[r]);
  }
}

// ---------------- qkv GEMM (MFMA) + windowed attention -> Ob bf16 ----------------
__global__ __launch_bounds__(256) void k_qkv_attn(const unsigned short* __restrict__ Xb,
    const unsigned short* __restrict__ qkvT, const float* __restrict__ qkv_b,
    unsigned short* __restrict__ Ob){
  __shared__ __align__(16) unsigned short qb[64][136];
  __shared__ __align__(16) unsigned short kb[64][136];
  __shared__ __align__(16) unsigned short vb[64][136];
  int t = threadIdx.x, lane = t & 63, wv = t >> 6;
  int m = lane & 15, q = lane >> 4;
  int rbase = blockIdx.x*64;
  int row = rbase + wv*16 + m;
  short8 af[4];
  const short8* ap = (const short8*)(Xb + (size_t)row*128);
  #pragma unroll
  for(int kk=0;kk<4;kk++) af[kk] = ap[kk*4+q];
  for(int nt=0; nt<24; nt++){
    int n0 = nt*16;
    float4v acc = {0.f,0.f,0.f,0.f};
    const short8* bp = (const short8*)(qkvT + (size_t)(n0 + m)*128);
    #pragma unroll
    for(int kk=0;kk<4;kk++)
      acc = __builtin_amdgcn_mfma_f32_16x16x32_bf16(af[kk], bp[kk*4+q], acc, 0,0,0);
    int col = n0 + m;
    float bias = qkv_b[col];
    unsigned short* dst = (col<128)? &qb[0][0] : (col<256? &kb[0][0] : &vb[0][0]);
    int cl = col & 127;
    #pragma unroll
    for(int j=0;j<4;j++){
      int rr = wv*16 + q*4 + j;
      dst[rr*136 + cl] = f2bf(acc[j] + bias);
    }
  }
  __syncthreads();
  // attention: thread = (window=t>>6, head=(t>>4)&3, qrow=t&15); all data wave-local
  int win = t >> 6, head = (t>>4)&3, qr = t & 15;
  const float scale = 0.17677669529663687f;  // 1/sqrt(32)
  float qv[32];
  load8f(&qb[win*16+qr][head*32+0],  qv+0);
  load8f(&qb[win*16+qr][head*32+8],  qv+8);
  load8f(&qb[win*16+qr][head*32+16], qv+16);
  load8f(&qb[win*16+qr][head*32+24], qv+24);
  float s[16];
  #pragma unroll
  for(int k=0;k<16;k++){
    float kvv[32];
    load8f(&kb[win*16+k][head*32+0],  kvv+0);
    load8f(&kb[win*16+k][head*32+8],  kvv+8);
    load8f(&kb[win*16+k][head*32+16], kvv+16);
    load8f(&kb[win*16+k][head*32+24], kvv+24);
    float a=0.f;
    #pragma unroll
    for(int d=0;d<32;d++) a += qv[d]*kvv[d];
    s[k]=a*scale;
  }
  float mx=s[0];
  #pragma unroll
  for(int k=1;k<16;k++) mx=fmaxf(mx,s[k]);
  float sum=0.f;
  #pragma unroll
  for(int k=0;k<16;k++){ s[k]=__expf(s[k]-mx); sum+=s[k]; }
  float inv=1.f/sum;
  float o[32];
  #pragma unroll
  for(int d=0;d<32;d++) o[d]=0.f;
  #pragma unroll
  for(int k=0;k<16;k++){
    float p = s[k]*inv;
    float vvv[32];
    load8f(&vb[win*16+k][head*32+0],  vvv+0);
    load8f(&vb[win*16+k][head*32+8],  vvv+8);
    load8f(&vb[win*16+k][head*32+16], vvv+16);
    load8f(&vb[win*16+k][head*32+24], vvv+24);
    #pragma unroll
    for(int d=0;d<32;d++) o[d] += p*vvv[d];
  }
  union{unsigned short us[32]; uint4 u4[4];} pk;
  #pragma unroll
  for(int d=0;d<32;d++) pk.us[d]=f2bf(o[d]);
  uint4* op=(uint4*)(Ob + (size_t)(rbase + win*16 + qr)*128 + head*32);
  #pragma unroll
  for(int i=0;i<4;i++) op[i]=pk.u4[i];
}

// ---------------- generic 128x128 GEMM; MODE 0: bias+relu, MODE 1: bias+resid+LN --------
template<int MODE>
__global__ __launch_bounds__(256) void k_gemm128(const unsigned short* __restrict__ Ab,
    const unsigned short* __restrict__ WT, const float* __restrict__ bias,
    const unsigned short* __restrict__ resid, const float* __restrict__ lng,
    const float* __restrict__ lnb, unsigned short* __restrict__ outb){
  __shared__ float ef[64*132];
  int t=threadIdx.x, lane=t&63, wv=t>>6;
  int m=lane&15, q=lane>>4;
  int rbase=blockIdx.x*64;
  short8 af[4];
  const short8* ap=(const short8*)(Ab + (size_t)(rbase+wv*16+m)*128);
  #pragma unroll
  for(int kk=0;kk<4;kk++) af[kk]=ap[kk*4+q];
  #pragma unroll
  for(int nt=0;nt<8;nt++){
    float4v acc={0.f,0.f,0.f,0.f};
    const short8* bp=(const short8*)(WT + (size_t)(nt*16+m)*128);
    #pragma unroll
    for(int kk=0;kk<4;kk++)
      acc=__builtin_amdgcn_mfma_f32_16x16x32_bf16(af[kk],bp[kk*4+q],acc,0,0,0);
    int col=nt*16+m;
    float bv=bias[col];
    #pragma unroll
    for(int j=0;j<4;j++) ef[(wv*16+q*4+j)*132 + col]=acc[j]+bv;
  }
  __syncthreads();
  int r=t>>2, qq=t&3;
  float v[32];
  const float* er=&ef[r*132+qq*32];
  #pragma unroll
  for(int i=0;i<32;i++) v[i]=er[i];
  size_t gro=(size_t)(rbase+r)*128+qq*32;
  if(MODE==0){
    union{unsigned short us[32]; uint4 u4[4];} pk;
    #pragma unroll
    for(int i=0;i<32;i++) pk.us[i]=f2bf(fmaxf(v[i],0.f));
    uint4* op=(uint4*)(outb+gro);
    #pragma unroll
    for(int i=0;i<4;i++) op[i]=pk.u4[i];
  } else {
    add_resid32(v, resid+gro);
    ln_write32(v, qq*32, lng, lnb, outb+gro);
  }
}

// ---------------- fused MLP: fc1+gelu(LDS) + fc2 + resid + LN2 ----------------
__global__ __launch_bounds__(256) void k_mlp(const unsigned short* __restrict__ X2b,
    const unsigned short* __restrict__ fc1T, const float* __restrict__ fc1b,
    const unsigned short* __restrict__ fc2T, const float* __restrict__ fc2b,
    const float* __restrict__ lng, const float* __restrict__ lnb,
    unsigned short* __restrict__ Xbout){
  __shared__ __align__(16) unsigned short hb[64*512];   // 64 KB, 16B-block xor-swizzled
  int t=threadIdx.x, lane=t&63, wv=t>>6;
  int m=lane&15, q=lane>>4;
  int rbase=blockIdx.x*64;
  short8 af[4];
  const short8* ap=(const short8*)(X2b + (size_t)(rbase+wv*16+m)*128);
  #pragma unroll
  for(int kk=0;kk<4;kk++) af[kk]=ap[kk*4+q];
  // fc1 (N=512) in two halves of 16 col-tiles to bound registers
  for(int half=0; half<2; half++){
    float4v acc[16];
    #pragma unroll
    for(int i=0;i<16;i++) acc[i]=(float4v){0.f,0.f,0.f,0.f};
    #pragma unroll
    for(int nt=0;nt<16;nt++){
      int n0=(half*16+nt)*16;
      const short8* bp=(const short8*)(fc1T + (size_t)(n0+m)*128);
      #pragma unroll
      for(int kk=0;kk<4;kk++)
        acc[nt]=__builtin_amdgcn_mfma_f32_16x16x32_bf16(af[kk],bp[kk*4+q],acc[nt],0,0,0);
    }
    #pragma unroll
    for(int nt=0;nt<16;nt++){
      int col=(half*16+nt)*16+m;
      float bv=fc1b[col];
      int bblk = col>>3;
      #pragma unroll
      for(int j=0;j<4;j++){
        int rr=wv*16+q*4+j;
        float x=acc[nt][j]+bv;
        float gel = 0.5f*x*(1.f+erff(x*0.70710678118654752f));   // exact gelu
        hb[rr*512 + ((bblk ^ (rr&63))<<3) + (col&7)] = f2bf(gel);
      }
    }
  }
  __syncthreads();
  // fc2 (K=512, N=128)
  int arow = wv*16+m;
  short8 haf[16];
  #pragma unroll
  for(int kk=0;kk<16;kk++){
    int bb=kk*4+q;
    haf[kk]=*(const short8*)&hb[arow*512 + ((bb ^ (arow&63))<<3)];
  }
  float4v acc2[8];
  #pragma unroll
  for(int i=0;i<8;i++) acc2[i]=(float4v){0.f,0.f,0.f,0.f};
  #pragma unroll
  for(int nt=0;nt<8;nt++){
    const short8* bp=(const short8*)(fc2T + (size_t)(nt*16+m)*512);
    #pragma unroll
    for(int kk=0;kk<16;kk++)
      acc2[nt]=__builtin_amdgcn_mfma_f32_16x16x32_bf16(haf[kk],bp[kk*4+q],acc2[nt],0,0,0);
  }
  __syncthreads();           // hb reads done -> reuse as f32 epilogue buffer
  float* ef=(float*)hb;      // 64*132 floats = 33.8 KB
  #pragma unroll
  for(int nt=0;nt<8;nt++){
    int col=nt*16+m;
    float bv=fc2b[col];
    #pragma unroll
    for(int j=0;j<4;j++) ef[(wv*16+q*4+j)*132+col]=acc2[nt][j]+bv;
  }
  __syncthreads();
  int r=t>>2, qq=t&3;
  float v[32];
  #pragma unroll
  for(int i=0;i<32;i++) v[i]=ef[r*132+qq*32+i];
  size_t gro=(size_t)(rbase+r)*128+qq*32;
  add_resid32(v, X2b+gro);
  ln_write32(v, qq*32, lng, lnb, Xbout+gro);
}

// ---------------- standalone LN (final norm) ----------------
__global__ __launch_bounds__(256) void k_lnfinal(const unsigned short* __restrict__ Xb,
    const float* __restrict__ g, const float* __restrict__ b,
    unsigned short* __restrict__ Mb){
  int t=threadIdx.x;
  int r=t>>2, qq=t&3;
  size_t gro=(size_t)(blockIdx.x*64+r)*128+qq*32;
  float v[32];
  #pragma unroll
  for(int i=0;i<4;i++){
    uint4 u=((const uint4*)(Xb+gro))[i];
    const unsigned short* us=(const unsigned short*)&u;
    #pragma unroll
    for(int k=0;k<8;k++) v[i*8+k]=bf2f(us[k]);
  }
  ln_write32(v, qq*32, g, b, Mb+gro);
}

// ---------------- head final dot + labels (fp32 out) ----------------
__global__ __launch_bounds__(256) void k_head3(const unsigned short* __restrict__ H2b,
    const float* __restrict__ h3w, const float* __restrict__ h3b,
    const int* __restrict__ seeds_i, float* __restrict__ outf){
  int row=blockIdx.x*256+threadIdx.x;
  const uint4* rp=(const uint4*)(H2b+(size_t)row*128);
  float acc=h3b[0];
  #pragma unroll
  for(int i=0;i<8;i++){
    uint4 u=rp[i];
    const unsigned short* us=(const unsigned short*)&u;
    #pragma unroll
    for(int j=0;j<8;j++) acc += bf2f(us[j])*h3w[i*8+j];
  }
  float lab=fmaxf(acc+(float)seeds_i[row],0.f);
  outf[OUT_LABELS+row]=lab;
}

// ============================================================================
extern "C" void kernel_launch(void* const* d_in, const int* in_sizes, int n_in,
                              void* d_out, int out_size, void* d_ws, size_t ws_size,
                              hipStream_t stream) {
  const float* cost_volume=(const float*)d_in[0];
  const float* fmap1   =(const float*)d_in[1];
  const float* mlp_w1  =(const float*)d_in[2];
  const float* mlp_b1  =(const float*)d_in[3];
  const float* mlp_w2  =(const float*)d_in[4];
  const float* mlp_b2  =(const float*)d_in[5];
  const float* mlp_w3  =(const float*)d_in[6];
  const float* mlp_b3  =(const float*)d_in[7];
  const float* proj_w1 =(const float*)d_in[8];
  const float* proj_w2 =(const float*)d_in[9];
  const float* embed_w =(const float*)d_in[10];
  const float* embed_b =(const float*)d_in[11];
  const float* ctx_w   =(const float*)d_in[12];
  const float* ctx_b   =(const float*)d_in[13];
  const float* ln1_g   =(const float*)d_in[14];
  const float* ln1_b   =(const float*)d_in[15];
  const float* qkv_w   =(const float*)d_in[16];
  const float* qkv_b   =(const float*)d_in[17];
  const float* attn_w  =(const float*)d_in[18];
  const float* attn_b  =(const float*)d_in[19];
  const float* ln2_g   =(const float*)d_in[20];
  const float* ln2_b   =(const float*)d_in[21];
  const float* fc1_w   =(const float*)d_in[22];
  const float* fc1_b   =(const float*)d_in[23];
  const float* fc2_w   =(const float*)d_in[24];
  const float* fc2_b   =(const float*)d_in[25];
  const float* normf_g =(const float*)d_in[26];
  const float* normf_b =(const float*)d_in[27];
  const float* h1_w    =(const float*)d_in[28];
  const float* h1_b    =(const float*)d_in[29];
  const float* h2_w    =(const float*)d_in[30];
  const float* h2_b    =(const float*)d_in[31];
  const float* h3_w    =(const float*)d_in[32];
  const float* h3_b    =(const float*)d_in[33];
  float* outf = (float*)d_out;        // fp32 output: cv | prob | seeds | labels

  // workspace layout (bytes, 256-aligned)
  char* ws=(char*)d_ws;
  unsigned short* act    =(unsigned short*)(ws + 0);             // 104,857,600 B
  float*          tmp3   =(float*)(ws + 104857600);              //  13,107,200 B
  float*          musg   =(float*)(ws + 117964800);              //       2,048 B
  float*          ctxT   =(float*)(ws + 117966848);              //   6,553,600 B
  int*            seeds_i=(int*)  (ws + 124520448);              //     409,600 B
  unsigned short* Xb     =(unsigned short*)(ws + 124930048);     //  26,214,400 B
  unsigned short* X2b    =(unsigned short*)(ws + 151144448);     //  26,214,400 B
  unsigned short* wbf    =(unsigned short*)(ws + 177358848);     //     851,968 B
  const size_t NEEDED = 178210816;
  if (ws_size < NEEDED) return;
  // time-disjoint reuse of 'act' (104 MB):
  //  early (pre-stage-4): fT (6.55 MB) + BT3 (0.29 MB) for conv3
  //  late  (stage 4+):    Ob | Mb | H1b | H2b
  unsigned short* fT  = act;                               // [2,80,160,128] bf16
  unsigned short* BT3 = act + 3276800;                     // [128][1152] bf16
  unsigned short* Ob  = act;
  unsigned short* Mb  = Ob  + 13107200;
  unsigned short* H1b = Mb  + 13107200;
  unsigned short* H2b = H1b + 13107200;
  // bf16 transposed weights
  unsigned short* qkvT = wbf;             // 2 x [384][128]
  unsigned short* attnT= wbf + 98304;     // 2 x [128][128]
  unsigned short* fc1T = wbf + 131072;    // 2 x [512][128]
  unsigned short* fc2T = wbf + 262144;    // 2 x [128][512]
  unsigned short* h1T  = wbf + 393216;
  unsigned short* h2T  = wbf + 409600;

  // ---- merged weight conversion (1 launch) ----
  CvtArgs ca;
  int base = 0;
  auto seg=[&](int i,const float* s,unsigned short* d,int ks,int Nn,int cnt){
    ca.s[i].src=s; ca.s[i].dst=d; ca.s[i].ks=ks; ca.s[i].N=Nn; ca.s[i].base=base; base+=cnt;
  };
  seg(0, qkv_w,        qkvT,        7, 384, 49152);
  seg(1, qkv_w+49152,  qkvT+49152,  7, 384, 49152);
  seg(2, attn_w,       attnT,       7, 128, 16384);
  seg(3, attn_w+16384, attnT+16384, 7, 128, 16384);
  seg(4, fc1_w,        fc1T,        7, 512, 65536);
  seg(5, fc1_w+65536,  fc1T+65536,  7, 512, 65536);
  seg(6, fc2_w,        fc2T,        9, 128, 65536);
  seg(7, fc2_w+65536,  fc2T+65536,  9, 128, 65536);
  seg(8, h1_w,         h1T,         7, 128, 16384);
  seg(9, h2_w,         h2T,         7, 128, 16384);
  k_cvt_all<<<(base+255)/256,256,0,stream>>>(ca, base);
  k_cvtW3<<<576,256,0,stream>>>(proj_w1, BT3);
  k_fmapT<<<dim3(5,4,160), dim3(32,8), 0, stream>>>(fmap1, fT);

  // stage 1: transpose (cv -> d_out chunk 0, fp32) + cost filter + seeds
  k_transpose<<<dim3(5,4,1280), dim3(32,8), 0, stream>>>(cost_volume, outf);
  k_cost<<<N_,128,0,stream>>>(mlp_w1,mlp_b1, mlp_w2,mlp_b2, mlp_w3,mlp_b3, outf, seeds_i);

  // stage 2: context projection (conv3x3 via MFMA im2col)
  k_conv3<<<dim3(5,40,4),256,0,stream>>>(fT, BT3, tmp3);
  k_inorm<<<256,256,0,stream>>>(tmp3, musg);
  k_ctx<<<dim3(5,80,2),256,0,stream>>>(tmp3, musg, proj_w2, ctxT);

  // stage 3: embedding
  k_embed<<<6400,256,0,stream>>>(outf, ctxT, seeds_i, embed_w, embed_b, ctx_w, ctx_b, Xb);

  // stage 4: transformer (2 layers)
  for(int l=0;l<2;l++){
    k_qkv_attn<<<1600,256,0,stream>>>(Xb, qkvT + (size_t)l*49152, qkv_b + l*384, Ob);
    k_gemm128<1><<<1600,256,0,stream>>>(Ob, attnT + (size_t)l*16384, attn_b + l*128,
                                        Xb, ln1_g + l*128, ln1_b + l*128, X2b);
    k_mlp<<<1600,256,0,stream>>>(X2b, fc1T + (size_t)l*65536, fc1_b + l*512,
                                 fc2T + (size_t)l*65536, fc2_b + l*128,
                                 ln2_g + l*128, ln2_b + l*128, Xb);
  }

  // stage 5: final norm + head
  k_lnfinal<<<1600,256,0,stream>>>(Xb, normf_g, normf_b, Mb);
  k_gemm128<0><<<1600,256,0,stream>>>(Mb,  h1T, h1_b, nullptr, nullptr, nullptr, H1b);
  k_gemm128<0><<<1600,256,0,stream>>>(H1b, h2T, h2_b, nullptr, nullptr, nullptr, H2b);
  k_head3<<<400,256,0,stream>>>(H2b, h3_w, h3_b, seeds_i, outf);
}

// Round 4
// 1514.225 us; speedup vs baseline: 1.4309x; 1.1557x over previous
//
#include <hip/hip_runtime.h>
#include <hip/hip_bf16.h>
#include <math.h>

// ---------------- problem constants ----------------
#define B_   2
#define G_   8
#define D_   128
#define H_   80
#define W_   160
#define N_   (B_*H_*W_)     // 25600
#define P_   4
#define CTX_ 64
#define C_   128
#define FD_  128
#define NROWS (N_*P_)       // 102400

// output chunk offsets (FLOAT32 elements) — d_out is float* (ref outputs fp32/int32)
#define OUT_CV     ((size_t)0)
#define OUT_PROB   ((size_t)26214400)
#define OUT_SEEDS  ((size_t)29491200)
#define OUT_LABELS ((size_t)29593600)

typedef __attribute__((ext_vector_type(8))) short short8;
typedef __attribute__((ext_vector_type(4))) float float4v;
typedef __attribute__((ext_vector_type(2))) float v2f;

__device__ __forceinline__ float bf2f(unsigned short u){
  unsigned v = ((unsigned)u) << 16;
  return __builtin_bit_cast(float, v);
}
__device__ __forceinline__ unsigned short f2bf(float f){
  __hip_bfloat16 h = __float2bfloat16(f);   // RNE
  return __builtin_bit_cast(unsigned short, h);
}
__device__ __forceinline__ void load8f(const unsigned short* p, float* f){
  uint4 u = *(const uint4*)p;
  const unsigned short* us = (const unsigned short*)&u;
  #pragma unroll
  for(int i=0;i<8;i++) f[i]=bf2f(us[i]);
}
__device__ __forceinline__ void add_resid32(float* v, const unsigned short* rp){
  #pragma unroll
  for(int i=0;i<4;i++){
    uint4 u = ((const uint4*)rp)[i];
    const unsigned short* us=(const unsigned short*)&u;
    #pragma unroll
    for(int k=0;k<8;k++) v[i*8+k]+=bf2f(us[k]);
  }
}
// per-thread holds 32 cols (segment qq of 4); 4 consecutive lanes = one row
__device__ __forceinline__ void ln_write32(float* v, int colbase, const float* g, const float* b,
                                           unsigned short* dst){
  float s=0.f, sq=0.f;
  #pragma unroll
  for(int i=0;i<32;i++){ s+=v[i]; sq+=v[i]*v[i]; }
  s  += __shfl_xor(s,1);  sq += __shfl_xor(sq,1);
  s  += __shfl_xor(s,2);  sq += __shfl_xor(sq,2);
  float mu  = s*(1.f/128.f);
  float var = sq*(1.f/128.f) - mu*mu;
  float rs  = rsqrtf(var+1e-5f);
  union{unsigned short us[32]; uint4 u4[4];} pk;
  #pragma unroll
  for(int i=0;i<32;i++) pk.us[i]=f2bf((v[i]-mu)*rs*g[colbase+i]+b[colbase+i]);
  uint4* op=(uint4*)dst;
  #pragma unroll
  for(int i=0;i<4;i++) op[i]=pk.u4[i];
}

// ---------------- merged weight convert+transpose (10 segments in 1 launch) -------------
// dst[r] = bf16(src[(r & (K-1))*N + (r>>ks)])   with K = 1<<ks   (dst[n*K+k] = src[k*N+n])
struct CvtSeg { const float* src; unsigned short* dst; int ks; int N; int base; };
struct CvtArgs { CvtSeg s[10]; };
__global__ __launch_bounds__(256) void k_cvt_all(CvtArgs a, int grand_total){
  int i = blockIdx.x*256 + threadIdx.x;
  if(i >= grand_total) return;
  int seg = 0;
  #pragma unroll
  for(int s=1;s<10;s++) if(i >= a.s[s].base) seg = s;
  int r = i - a.s[seg].base;
  int ks = a.s[seg].ks;
  int k = r & ((1<<ks)-1);
  int n = r >> ks;
  a.s[seg].dst[r] = f2bf(a.s[seg].src[(size_t)k*a.s[seg].N + n]);
}

// ---------------- conv3 weight reorder: BT[co][tap*128+ci] = w[co][ci][tap] bf16 ---------
__global__ __launch_bounds__(256) void k_cvtW3(const float* __restrict__ w,
                                               unsigned short* __restrict__ BT){
  int i = blockIdx.x*256 + threadIdx.x;
  if(i < 128*1152){
    int co = i / 1152, rem = i % 1152;
    int tap = rem >> 7, ci = rem & 127;
    BT[i] = f2bf(w[((size_t)co*128 + ci)*9 + tap]);
  }
}

// ---------------- fmap transpose: [B,128,H,W] f32 -> fT [B,H,W,128] bf16 ----------------
__global__ __launch_bounds__(256) void k_fmapT(const float* __restrict__ fmap,
                                               unsigned short* __restrict__ fT){
  __shared__ float t[32][33];
  int w0 = blockIdx.x*32, c0 = blockIdx.y*32;
  int z = blockIdx.z; int b = z / H_; int h = z % H_;
  int tx = threadIdx.x, ty = threadIdx.y;   // 32 x 8
  #pragma unroll
  for(int i=0;i<4;i++){
    int c = c0 + ty + i*8;
    t[ty+i*8][tx] = fmap[(((size_t)b*FD_ + c)*H_ + h)*W_ + w0 + tx];
  }
  __syncthreads();
  #pragma unroll
  for(int i=0;i<4;i++){
    int wl = ty + i*8;
    fT[(((size_t)b*H_ + h)*W_ + w0 + wl)*128 + c0 + tx] = f2bf(t[tx][wl]);
  }
}

// ---------------- cost volume transpose: [B,G,D,H,W] -> cv[N,G,D] fp32 directly in d_out --
__global__ __launch_bounds__(256) void k_transpose(const float* __restrict__ cvol,
                                                   float* __restrict__ outf){
  __shared__ float t[32][33];
  int z = blockIdx.z;                 // bg*H + h ; bg = b*G+g
  int h = z % H_;  int bg = z / H_;
  int w0 = blockIdx.x*32, d0 = blockIdx.y*32;
  int tx = threadIdx.x, ty = threadIdx.y;   // 32 x 8
  #pragma unroll
  for(int i=0;i<4;i++){
    int d = d0 + ty + i*8;
    t[ty+i*8][tx] = cvol[(((size_t)bg*D_ + d)*H_ + h)*W_ + w0 + tx];
  }
  __syncthreads();
  int b = bg / G_, g = bg % G_;
  #pragma unroll
  for(int i=0;i<4;i++){
    int wl = ty + i*8;
    int n = (b*H_+h)*W_ + w0 + wl;
    size_t o = ((size_t)n*G_ + g)*D_ + d0 + tx;
    outf[OUT_CV + o] = t[tx][wl];
  }
}

// ---------------- cost filter: wave-per-pixel, float2/pk-fma, shuffle reductions ---------
// lane L owns d=2L,2L+1. LDS: A[16][132] (cv then h2), B[8][132] (h1); pads [0,1],[130,131]=0
__global__ __launch_bounds__(256) void k_cost(
    const float* __restrict__ w1, const float* __restrict__ b1,
    const float* __restrict__ w2, const float* __restrict__ b2,
    const float* __restrict__ w3, const float* __restrict__ b3,
    float* __restrict__ outf, int* __restrict__ seeds_i){
  __shared__ float As[4][16*132];
  __shared__ float Bs[4][8*132];
  int t = threadIdx.x, wv = t>>6, lane = t&63;
  int n = blockIdx.x*4 + wv;
  float* A  = As[wv];
  float* Bb = Bs[wv];
  // zero the per-channel pads (24 channels x 2 sides)
  if(lane < 48){
    int ch = lane>>1, side = lane&1;
    float* buf = (ch<16)? (A + ch*132) : (Bb + (ch-16)*132);
    *(v2f*)(buf + (side?130:0)) = (v2f){0.f,0.f};
  }
  // stage cv[n][g][:] into A[g], data at [2..129]
  const float* cvp = outf + OUT_CV + (size_t)n*(G_*D_);
  #pragma unroll
  for(int g=0; g<8; g++)
    *(v2f*)(A + g*132 + 2 + 2*lane) = *(const v2f*)(cvp + g*128 + 2*lane);
  __syncthreads();
  // conv1: 8 -> 8, k5, relu
  v2f a1[8];
  #pragma unroll
  for(int c=0;c<8;c++) a1[c] = (v2f){b1[c], b1[c]};
  #pragma unroll
  for(int g=0; g<8; g++){
    const float* base = A + g*132 + 2*lane;       // [0] = d-2
    v2f vm = *(const v2f*)(base);
    v2f vc = *(const v2f*)(base+2);
    v2f vp = *(const v2f*)(base+4);
    v2f tap0=vm, tap1=(v2f){vm.y,vc.x}, tap2=vc, tap3=(v2f){vc.y,vp.x}, tap4=vp;
    #pragma unroll
    for(int c=0;c<8;c++){
      const float* wp = w1 + (c*8+g)*5;
      a1[c] = __builtin_elementwise_fma(tap0, (v2f){wp[0],wp[0]}, a1[c]);
      a1[c] = __builtin_elementwise_fma(tap1, (v2f){wp[1],wp[1]}, a1[c]);
      a1[c] = __builtin_elementwise_fma(tap2, (v2f){wp[2],wp[2]}, a1[c]);
      a1[c] = __builtin_elementwise_fma(tap3, (v2f){wp[3],wp[3]}, a1[c]);
      a1[c] = __builtin_elementwise_fma(tap4, (v2f){wp[4],wp[4]}, a1[c]);
    }
  }
  #pragma unroll
  for(int c=0;c<8;c++)
    *(v2f*)(Bb + c*132 + 2 + 2*lane) = (v2f){fmaxf(a1[c].x,0.f), fmaxf(a1[c].y,0.f)};
  __syncthreads();
  // conv2: 8 -> 16, k5, relu
  v2f a2[16];
  #pragma unroll
  for(int c=0;c<16;c++) a2[c] = (v2f){b2[c], b2[c]};
  #pragma unroll
  for(int g=0; g<8; g++){
    const float* base = Bb + g*132 + 2*lane;
    v2f vm = *(const v2f*)(base);
    v2f vc = *(const v2f*)(base+2);
    v2f vp = *(const v2f*)(base+4);
    v2f tap0=vm, tap1=(v2f){vm.y,vc.x}, tap2=vc, tap3=(v2f){vc.y,vp.x}, tap4=vp;
    #pragma unroll
    for(int c=0;c<16;c++){
      const float* wp = w2 + (c*8+g)*5;
      a2[c] = __builtin_elementwise_fma(tap0, (v2f){wp[0],wp[0]}, a2[c]);
      a2[c] = __builtin_elementwise_fma(tap1, (v2f){wp[1],wp[1]}, a2[c]);
      a2[c] = __builtin_elementwise_fma(tap2, (v2f){wp[2],wp[2]}, a2[c]);
      a2[c] = __builtin_elementwise_fma(tap3, (v2f){wp[3],wp[3]}, a2[c]);
      a2[c] = __builtin_elementwise_fma(tap4, (v2f){wp[4],wp[4]}, a2[c]);
    }
  }
  #pragma unroll
  for(int c=0;c<16;c++)
    *(v2f*)(A + c*132 + 2 + 2*lane) = (v2f){fmaxf(a2[c].x,0.f), fmaxf(a2[c].y,0.f)};
  __syncthreads();
  // conv3: 16 -> 1, k5
  v2f cost = (v2f){b3[0], b3[0]};
  #pragma unroll
  for(int g=0; g<16; g++){
    const float* base = A + g*132 + 2*lane;
    v2f vm = *(const v2f*)(base);
    v2f vc = *(const v2f*)(base+2);
    v2f vp = *(const v2f*)(base+4);
    v2f tap0=vm, tap1=(v2f){vm.y,vc.x}, tap2=vc, tap3=(v2f){vc.y,vp.x}, tap4=vp;
    const float* wp = w3 + g*5;
    cost = __builtin_elementwise_fma(tap0, (v2f){wp[0],wp[0]}, cost);
    cost = __builtin_elementwise_fma(tap1, (v2f){wp[1],wp[1]}, cost);
    cost = __builtin_elementwise_fma(tap2, (v2f){wp[2],wp[2]}, cost);
    cost = __builtin_elementwise_fma(tap3, (v2f){wp[3],wp[3]}, cost);
    cost = __builtin_elementwise_fma(tap4, (v2f){wp[4],wp[4]}, cost);
  }
  // wave softmax (exact expf, matches passing version)
  float mx = fmaxf(cost.x, cost.y);
  #pragma unroll
  for(int off=32; off>0; off>>=1) mx = fmaxf(mx, __shfl_xor(mx, off));
  v2f e = (v2f){expf(cost.x-mx), expf(cost.y-mx)};
  float sm = e.x + e.y;
  #pragma unroll
  for(int off=32; off>0; off>>=1) sm += __shfl_xor(sm, off);
  float inv = 1.f/sm;
  v2f prob = (v2f){e.x*inv, e.y*inv};
  *(v2f*)(outf + OUT_PROB + (size_t)n*D_ + 2*lane) = prob;
  // local-max suppression
  float pm = __shfl(prob.y, lane-1);  if(lane==0)  pm = -1e30f;   // prob[2L-1]
  float pp = __shfl(prob.x, lane+1);  if(lane==63) pp = -1e30f;   // prob[2L+2]
  float plx = fmaxf(fmaxf(pm, prob.x), prob.y);
  float ply = fmaxf(fmaxf(prob.x, prob.y), pp);
  v2f pv;
  pv.x = ((prob.x != plx) && (prob.x > 1e-3f)) ? 1e-3f : prob.x;
  pv.y = ((prob.y != ply) && (prob.y > 1e-3f)) ? 1e-3f : prob.y;
  // top-4 via wave argmax butterflies (tie -> lower index)
  #pragma unroll
  for(int p=0; p<P_; p++){
    float bv; int bi;
    if(pv.y > pv.x){ bv=pv.y; bi=2*lane+1; } else { bv=pv.x; bi=2*lane; }
    #pragma unroll
    for(int off=1; off<64; off<<=1){
      float ov = __shfl_xor(bv, off);
      int   oi = __shfl_xor(bi, off);
      if(ov > bv || (ov == bv && oi < bi)){ bv=ov; bi=oi; }
    }
    if(lane==0){
      seeds_i[n*P_+p] = bi;
      outf[OUT_SEEDS + (size_t)n*P_ + p] = (float)bi;
    }
    if(bi == 2*lane)   pv.x = -1e30f;
    if(bi == 2*lane+1) pv.y = -1e30f;
  }
}

// ---------------- conv3x3 as MFMA im2col GEMM: fT[B,H,W,128]bf16 × BT[128co][1152] ------
__global__ __launch_bounds__(256) void k_conv3(const unsigned short* __restrict__ fT,
                                               const unsigned short* __restrict__ BT,
                                               float* __restrict__ tmp3){
  __shared__ __align__(16) unsigned short hal[4*34*136];  // [r][w][c], c padded to 136
  int t = threadIdx.x, lane = t & 63, wv = t >> 6;
  int m = lane & 15, q = lane >> 4;
  int w0 = blockIdx.x*32;            // 5
  int h0 = blockIdx.y*2;             // 40
  int bz = blockIdx.z;               // 4: b = bz>>1, co half = bz&1
  int b  = bz >> 1;
  int co0 = (bz & 1)*64;
  for(int idx=t; idx<4*34*16; idx+=256){
    int chunk = idx & 15;            // 8-ch block
    int pos = idx >> 4;              // r*34+wl
    int r = pos / 34, wl = pos % 34;
    int gh = h0 - 1 + r, gw = w0 - 1 + wl;
    uint4 v = {0u,0u,0u,0u};
    if(gh>=0 && gh<H_ && gw>=0 && gw<W_)
      v = *(const uint4*)(fT + ((((size_t)b*H_+gh)*W_+gw)<<7) + chunk*8);
    *(uint4*)&hal[pos*136 + chunk*8] = v;
  }
  __syncthreads();
  int rowt = wv >> 1, wcol = (wv & 1)*16;
  float4v acc[4];
  #pragma unroll
  for(int i=0;i<4;i++) acc[i]=(float4v){0.f,0.f,0.f,0.f};
  #pragma unroll
  for(int ky=0;ky<3;ky++){
    #pragma unroll
    for(int kx=0;kx<3;kx++){
      int tap = ky*3+kx;
      const unsigned short* abase = &hal[((rowt+ky)*34 + wcol + m + kx)*136 + q*8];
      short8 af[4];
      #pragma unroll
      for(int kk=0;kk<4;kk++) af[kk] = *(const short8*)(abase + kk*32);
      #pragma unroll
      for(int nt=0;nt<4;nt++){
        const short8* bp = (const short8*)(BT + (size_t)(co0 + nt*16 + m)*1152 + tap*128);
        #pragma unroll
        for(int kk=0;kk<4;kk++)
          acc[nt] = __builtin_amdgcn_mfma_f32_16x16x32_bf16(af[kk], bp[kk*4+q], acc[nt], 0,0,0);
      }
    }
  }
  int h = h0 + rowt;
  #pragma unroll
  for(int nt=0;nt<4;nt++){
    int co = co0 + nt*16 + m;
    *(float4v*)(tmp3 + (((size_t)b*128+co)*H_ + h)*W_ + w0 + wcol + q*4) = acc[nt];
  }
}

// ---------------- instance norm stats ----------------
__global__ __launch_bounds__(256) void k_inorm(const float* __restrict__ tmp3,
                                               float* __restrict__ musg){
  int bc = blockIdx.x;
  const float* p = tmp3 + (size_t)bc*H_*W_;
  float s=0.f, sq=0.f;
  for(int i=threadIdx.x;i<H_*W_;i+=256){ float v=p[i]; s+=v; sq+=v*v; }
  __shared__ float rs_[256], rq_[256];
  rs_[threadIdx.x]=s; rq_[threadIdx.x]=sq; __syncthreads();
  for(int st=128;st>0;st>>=1){
    if(threadIdx.x<st){ rs_[threadIdx.x]+=rs_[threadIdx.x+st]; rq_[threadIdx.x]+=rq_[threadIdx.x+st]; }
    __syncthreads();
  }
  if(threadIdx.x==0){
    float mu = rs_[0]/(float)(H_*W_);
    float var = rq_[0]/(float)(H_*W_) - mu*mu;
    musg[bc*2]=mu; musg[bc*2+1]=rsqrtf(var+1e-5f);
  }
}

// ---------------- norm+relu+conv1x1 -> ctxT[64][N] ----------------
__global__ __launch_bounds__(256) void k_ctx(const float* __restrict__ tmp3,
                                             const float* __restrict__ musg,
                                             const float* __restrict__ w2,
                                             float* __restrict__ ctxT){
  __shared__ float nl[128][33];
  int w0 = blockIdx.x*32; int h = blockIdx.y; int b = blockIdx.z;
  int t = threadIdx.x;
  for(int idx=t; idx<128*32; idx+=256){
    int c = idx>>5, wl = idx&31;
    float v = tmp3[(((size_t)b*128+c)*H_+h)*W_+w0+wl];
    v = (v - musg[(b*128+c)*2]) * musg[(b*128+c)*2+1];
    nl[c][wl] = fmaxf(v, 0.f);
  }
  __syncthreads();
  int wl = t & 31, cg = t >> 5;
  float acc[8]={0.f,0.f,0.f,0.f,0.f,0.f,0.f,0.f};
  for(int c=0;c<128;c++){
    float v = nl[c][wl];
    #pragma unroll
    for(int j=0;j<8;j++) acc[j] += v * w2[(size_t)(cg*8+j)*128 + c];
  }
  int n = (b*H_+h)*W_ + w0 + wl;
  #pragma unroll
  for(int j=0;j<8;j++) ctxT[(size_t)(cg*8+j)*N_ + n] = acc[j];
}

// ---------------- seed embedding + ctx projection -> Xb bf16 [NROWS,128] ----------------
__global__ __launch_bounds__(256) void k_embed(const float* __restrict__ outf,
    const float* __restrict__ ctxT, const int* __restrict__ seeds_i,
    const float* __restrict__ embed_w, const float* __restrict__ embed_b,
    const float* __restrict__ ctx_w, const float* __restrict__ ctx_b,
    unsigned short* __restrict__ Xb){
  __shared__ float feats[16][72];
  __shared__ float cvv[4][64];
  const float* cvf = outf + OUT_CV;
  int n0 = blockIdx.x*4;
  int t = threadIdx.x;
  for(int idx=t; idx<16*72; idx+=256){
    int r = idx/72, j = idx%72;
    int n = n0 + (r>>2), p = r&3;
    int sd = seeds_i[n*4+p];
    int g = j/9, tt = j%9;
    int di = sd + tt - 4; di = di<0?0:(di>127?127:di);
    feats[r][j] = cvf[((size_t)n*8+g)*128 + di];
  }
  for(int idx=t; idx<4*64; idx+=256){
    int nl_ = idx>>6, k = idx&63;
    cvv[nl_][k] = ctxT[(size_t)k*N_ + n0+nl_];
  }
  __syncthreads();
  int col = t & 127, rg = t >> 7;
  float acc[8];
  float bb = embed_b[col] + ctx_b[col];
  #pragma unroll
  for(int r=0;r<8;r++) acc[r]=bb;
  for(int j=0;j<72;j++){
    float wv = embed_w[(size_t)j*128+col];
    #pragma unroll
    for(int r=0;r<8;r++) acc[r] += feats[rg*8+r][j]*wv;
  }
  for(int k=0;k<64;k++){
    float wv = ctx_w[(size_t)k*128+col];
    #pragma unroll
    for(int r=0;r<8;r++) acc[r] += cvv[(rg*8+r)>>2][k]*wv;
  }
  #pragma unroll
  for(int r=0;r<8;r++){
    int row = n0*4 + rg*8 + r;
    Xb[(size_t)row*128 + col] = f2bf(acc[r]);
  }
}

// ---------------- qkv GEMM (MFMA) + windowed attention -> Ob bf16 ----------------
__global__ __launch_bounds__(256) void k_qkv_attn(const unsigned short* __restrict__ Xb,
    const unsigned short* __restrict__ qkvT, const float* __restrict__ qkv_b,
    unsigned short* __restrict__ Ob){
  __shared__ __align__(16) unsigned short qb[64][136];
  __shared__ __align__(16) unsigned short kb[64][136];
  __shared__ __align__(16) unsigned short vb[64][136];
  int t = threadIdx.x, lane = t & 63, wv = t >> 6;
  int m = lane & 15, q = lane >> 4;
  int rbase = blockIdx.x*64;
  int row = rbase + wv*16 + m;
  short8 af[4];
  const short8* ap = (const short8*)(Xb + (size_t)row*128);
  #pragma unroll
  for(int kk=0;kk<4;kk++) af[kk] = ap[kk*4+q];
  for(int nt=0; nt<24; nt++){
    int n0 = nt*16;
    float4v acc = {0.f,0.f,0.f,0.f};
    const short8* bp = (const short8*)(qkvT + (size_t)(n0 + m)*128);
    #pragma unroll
    for(int kk=0;kk<4;kk++)
      acc = __builtin_amdgcn_mfma_f32_16x16x32_bf16(af[kk], bp[kk*4+q], acc, 0,0,0);
    int col = n0 + m;
    float bias = qkv_b[col];
    unsigned short* dst = (col<128)? &qb[0][0] : (col<256? &kb[0][0] : &vb[0][0]);
    int cl = col & 127;
    #pragma unroll
    for(int j=0;j<4;j++){
      int rr = wv*16 + q*4 + j;
      dst[rr*136 + cl] = f2bf(acc[j] + bias);
    }
  }
  __syncthreads();
  int win = t >> 6, head = (t>>4)&3, qr = t & 15;
  const float scale = 0.17677669529663687f;  // 1/sqrt(32)
  float qv[32];
  load8f(&qb[win*16+qr][head*32+0],  qv+0);
  load8f(&qb[win*16+qr][head*32+8],  qv+8);
  load8f(&qb[win*16+qr][head*32+16], qv+16);
  load8f(&qb[win*16+qr][head*32+24], qv+24);
  float s[16];
  #pragma unroll
  for(int k=0;k<16;k++){
    float kvv[32];
    load8f(&kb[win*16+k][head*32+0],  kvv+0);
    load8f(&kb[win*16+k][head*32+8],  kvv+8);
    load8f(&kb[win*16+k][head*32+16], kvv+16);
    load8f(&kb[win*16+k][head*32+24], kvv+24);
    float a=0.f;
    #pragma unroll
    for(int d=0;d<32;d++) a += qv[d]*kvv[d];
    s[k]=a*scale;
  }
  float mx=s[0];
  #pragma unroll
  for(int k=1;k<16;k++) mx=fmaxf(mx,s[k]);
  float sum=0.f;
  #pragma unroll
  for(int k=0;k<16;k++){ s[k]=__expf(s[k]-mx); sum+=s[k]; }
  float inv=1.f/sum;
  float o[32];
  #pragma unroll
  for(int d=0;d<32;d++) o[d]=0.f;
  #pragma unroll
  for(int k=0;k<16;k++){
    float p = s[k]*inv;
    float vvv[32];
    load8f(&vb[win*16+k][head*32+0],  vvv+0);
    load8f(&vb[win*16+k][head*32+8],  vvv+8);
    load8f(&vb[win*16+k][head*32+16], vvv+16);
    load8f(&vb[win*16+k][head*32+24], vvv+24);
    #pragma unroll
    for(int d=0;d<32;d++) o[d] += p*vvv[d];
  }
  union{unsigned short us[32]; uint4 u4[4];} pk;
  #pragma unroll
  for(int d=0;d<32;d++) pk.us[d]=f2bf(o[d]);
  uint4* op=(uint4*)(Ob + (size_t)(rbase + win*16 + qr)*128 + head*32);
  #pragma unroll
  for(int i=0;i<4;i++) op[i]=pk.u4[i];
}

// ---------------- generic 128x128 GEMM; MODE 0: bias+relu, MODE 1: bias+resid+LN --------
template<int MODE>
__global__ __launch_bounds__(256) void k_gemm128(const unsigned short* __restrict__ Ab,
    const unsigned short* __restrict__ WT, const float* __restrict__ bias,
    const unsigned short* __restrict__ resid, const float* __restrict__ lng,
    const float* __restrict__ lnb, unsigned short* __restrict__ outb){
  __shared__ float ef[64*132];
  int t=threadIdx.x, lane=t&63, wv=t>>6;
  int m=lane&15, q=lane>>4;
  int rbase=blockIdx.x*64;
  short8 af[4];
  const short8* ap=(const short8*)(Ab + (size_t)(rbase+wv*16+m)*128);
  #pragma unroll
  for(int kk=0;kk<4;kk++) af[kk]=ap[kk*4+q];
  #pragma unroll
  for(int nt=0;nt<8;nt++){
    float4v acc={0.f,0.f,0.f,0.f};
    const short8* bp=(const short8*)(WT + (size_t)(nt*16+m)*128);
    #pragma unroll
    for(int kk=0;kk<4;kk++)
      acc=__builtin_amdgcn_mfma_f32_16x16x32_bf16(af[kk],bp[kk*4+q],acc,0,0,0);
    int col=nt*16+m;
    float bv=bias[col];
    #pragma unroll
    for(int j=0;j<4;j++) ef[(wv*16+q*4+j)*132 + col]=acc[j]+bv;
  }
  __syncthreads();
  int r=t>>2, qq=t&3;
  float v[32];
  const float* er=&ef[r*132+qq*32];
  #pragma unroll
  for(int i=0;i<32;i++) v[i]=er[i];
  size_t gro=(size_t)(rbase+r)*128+qq*32;
  if(MODE==0){
    union{unsigned short us[32]; uint4 u4[4];} pk;
    #pragma unroll
    for(int i=0;i<32;i++) pk.us[i]=f2bf(fmaxf(v[i],0.f));
    uint4* op=(uint4*)(outb+gro);
    #pragma unroll
    for(int i=0;i<4;i++) op[i]=pk.u4[i];
  } else {
    add_resid32(v, resid+gro);
    ln_write32(v, qq*32, lng, lnb, outb+gro);
  }
}

// ---------------- fused MLP: fc1+gelu(LDS) + fc2 + resid + LN2 ----------------
__global__ __launch_bounds__(256) void k_mlp(const unsigned short* __restrict__ X2b,
    const unsigned short* __restrict__ fc1T, const float* __restrict__ fc1b,
    const unsigned short* __restrict__ fc2T, const float* __restrict__ fc2b,
    const float* __restrict__ lng, const float* __restrict__ lnb,
    unsigned short* __restrict__ Xbout){
  __shared__ __align__(16) unsigned short hb[64*512];   // 64 KB, 16B-block xor-swizzled
  int t=threadIdx.x, lane=t&63, wv=t>>6;
  int m=lane&15, q=lane>>4;
  int rbase=blockIdx.x*64;
  short8 af[4];
  const short8* ap=(const short8*)(X2b + (size_t)(rbase+wv*16+m)*128);
  #pragma unroll
  for(int kk=0;kk<4;kk++) af[kk]=ap[kk*4+q];
  for(int half=0; half<2; half++){
    float4v acc[16];
    #pragma unroll
    for(int i=0;i<16;i++) acc[i]=(float4v){0.f,0.f,0.f,0.f};
    #pragma unroll
    for(int nt=0;nt<16;nt++){
      int n0=(half*16+nt)*16;
      const short8* bp=(const short8*)(fc1T + (size_t)(n0+m)*128);
      #pragma unroll
      for(int kk=0;kk<4;kk++)
        acc[nt]=__builtin_amdgcn_mfma_f32_16x16x32_bf16(af[kk],bp[kk*4+q],acc[nt],0,0,0);
    }
    #pragma unroll
    for(int nt=0;nt<16;nt++){
      int col=(half*16+nt)*16+m;
      float bv=fc1b[col];
      int bblk = col>>3;
      #pragma unroll
      for(int j=0;j<4;j++){
        int rr=wv*16+q*4+j;
        float x=acc[nt][j]+bv;
        float gel = 0.5f*x*(1.f+erff(x*0.70710678118654752f));   // exact gelu
        hb[rr*512 + ((bblk ^ (rr&63))<<3) + (col&7)] = f2bf(gel);
      }
    }
  }
  __syncthreads();
  int arow = wv*16+m;
  short8 haf[16];
  #pragma unroll
  for(int kk=0;kk<16;kk++){
    int bb=kk*4+q;
    haf[kk]=*(const short8*)&hb[arow*512 + ((bb ^ (arow&63))<<3)];
  }
  float4v acc2[8];
  #pragma unroll
  for(int i=0;i<8;i++) acc2[i]=(float4v){0.f,0.f,0.f,0.f};
  #pragma unroll
  for(int nt=0;nt<8;nt++){
    const short8* bp=(const short8*)(fc2T + (size_t)(nt*16+m)*512);
    #pragma unroll
    for(int kk=0;kk<16;kk++)
      acc2[nt]=__builtin_amdgcn_mfma_f32_16x16x32_bf16(haf[kk],bp[kk*4+q],acc2[nt],0,0,0);
  }
  __syncthreads();
  float* ef=(float*)hb;
  #pragma unroll
  for(int nt=0;nt<8;nt++){
    int col=nt*16+m;
    float bv=fc2b[col];
    #pragma unroll
    for(int j=0;j<4;j++) ef[(wv*16+q*4+j)*132+col]=acc2[nt][j]+bv;
  }
  __syncthreads();
  int r=t>>2, qq=t&3;
  float v[32];
  #pragma unroll
  for(int i=0;i<32;i++) v[i]=ef[r*132+qq*32+i];
  size_t gro=(size_t)(rbase+r)*128+qq*32;
  add_resid32(v, X2b+gro);
  ln_write32(v, qq*32, lng, lnb, Xbout+gro);
}

// ---------------- standalone LN (final norm) ----------------
__global__ __launch_bounds__(256) void k_lnfinal(const unsigned short* __restrict__ Xb,
    const float* __restrict__ g, const float* __restrict__ b,
    unsigned short* __restrict__ Mb){
  int t=threadIdx.x;
  int r=t>>2, qq=t&3;
  size_t gro=(size_t)(blockIdx.x*64+r)*128+qq*32;
  float v[32];
  #pragma unroll
  for(int i=0;i<4;i++){
    uint4 u=((const uint4*)(Xb+gro))[i];
    const unsigned short* us=(const unsigned short*)&u;
    #pragma unroll
    for(int k=0;k<8;k++) v[i*8+k]=bf2f(us[k]);
  }
  ln_write32(v, qq*32, g, b, Mb+gro);
}

// ---------------- head final dot + labels (fp32 out) ----------------
__global__ __launch_bounds__(256) void k_head3(const unsigned short* __restrict__ H2b,
    const float* __restrict__ h3w, const float* __restrict__ h3b,
    const int* __restrict__ seeds_i, float* __restrict__ outf){
  int row=blockIdx.x*256+threadIdx.x;
  const uint4* rp=(const uint4*)(H2b+(size_t)row*128);
  float acc=h3b[0];
  #pragma unroll
  for(int i=0;i<8;i++){
    uint4 u=rp[i];
    const unsigned short* us=(const unsigned short*)&u;
    #pragma unroll
    for(int j=0;j<8;j++) acc += bf2f(us[j])*h3w[i*8+j];
  }
  float lab=fmaxf(acc+(float)seeds_i[row],0.f);
  outf[OUT_LABELS+row]=lab;
}

// ============================================================================
extern "C" void kernel_launch(void* const* d_in, const int* in_sizes, int n_in,
                              void* d_out, int out_size, void* d_ws, size_t ws_size,
                              hipStream_t stream) {
  const float* cost_volume=(const float*)d_in[0];
  const float* fmap1   =(const float*)d_in[1];
  const float* mlp_w1  =(const float*)d_in[2];
  const float* mlp_b1  =(const float*)d_in[3];
  const float* mlp_w2  =(const float*)d_in[4];
  const float* mlp_b2  =(const float*)d_in[5];
  const float* mlp_w3  =(const float*)d_in[6];
  const float* mlp_b3  =(const float*)d_in[7];
  const float* proj_w1 =(const float*)d_in[8];
  const float* proj_w2 =(const float*)d_in[9];
  const float* embed_w =(const float*)d_in[10];
  const float* embed_b =(const float*)d_in[11];
  const float* ctx_w   =(const float*)d_in[12];
  const float* ctx_b   =(const float*)d_in[13];
  const float* ln1_g   =(const float*)d_in[14];
  const float* ln1_b   =(const float*)d_in[15];
  const float* qkv_w   =(const float*)d_in[16];
  const float* qkv_b   =(const float*)d_in[17];
  const float* attn_w  =(const float*)d_in[18];
  const float* attn_b  =(const float*)d_in[19];
  const float* ln2_g   =(const float*)d_in[20];
  const float* ln2_b   =(const float*)d_in[21];
  const float* fc1_w   =(const float*)d_in[22];
  const float* fc1_b   =(const float*)d_in[23];
  const float* fc2_w   =(const float*)d_in[24];
  const float* fc2_b   =(const float*)d_in[25];
  const float* normf_g =(const float*)d_in[26];
  const float* normf_b =(const float*)d_in[27];
  const float* h1_w    =(const float*)d_in[28];
  const float* h1_b    =(const float*)d_in[29];
  const float* h2_w    =(const float*)d_in[30];
  const float* h2_b    =(const float*)d_in[31];
  const float* h3_w    =(const float*)d_in[32];
  const float* h3_b    =(const float*)d_in[33];
  float* outf = (float*)d_out;        // fp32 output: cv | prob | seeds | labels

  // workspace layout (bytes, 256-aligned)
  char* ws=(char*)d_ws;
  unsigned short* act    =(unsigned short*)(ws + 0);             // 104,857,600 B
  float*          tmp3   =(float*)(ws + 104857600);              //  13,107,200 B
  float*          musg   =(float*)(ws + 117964800);              //       2,048 B
  float*          ctxT   =(float*)(ws + 117966848);              //   6,553,600 B
  int*            seeds_i=(int*)  (ws + 124520448);              //     409,600 B
  unsigned short* Xb     =(unsigned short*)(ws + 124930048);     //  26,214,400 B
  unsigned short* X2b    =(unsigned short*)(ws + 151144448);     //  26,214,400 B
  unsigned short* wbf    =(unsigned short*)(ws + 177358848);     //     851,968 B
  const size_t NEEDED = 178210816;
  if (ws_size < NEEDED) return;
  unsigned short* fT  = act;                               // [2,80,160,128] bf16
  unsigned short* BT3 = act + 3276800;                     // [128][1152] bf16
  unsigned short* Ob  = act;
  unsigned short* Mb  = Ob  + 13107200;
  unsigned short* H1b = Mb  + 13107200;
  unsigned short* H2b = H1b + 13107200;
  unsigned short* qkvT = wbf;             // 2 x [384][128]
  unsigned short* attnT= wbf + 98304;     // 2 x [128][128]
  unsigned short* fc1T = wbf + 131072;    // 2 x [512][128]
  unsigned short* fc2T = wbf + 262144;    // 2 x [128][512]
  unsigned short* h1T  = wbf + 393216;
  unsigned short* h2T  = wbf + 409600;

  // ---- merged weight conversion (1 launch) ----
  CvtArgs ca;
  int base = 0;
  auto seg=[&](int i,const float* s,unsigned short* d,int ks,int Nn,int cnt){
    ca.s[i].src=s; ca.s[i].dst=d; ca.s[i].ks=ks; ca.s[i].N=Nn; ca.s[i].base=base; base+=cnt;
  };
  seg(0, qkv_w,        qkvT,        7, 384, 49152);
  seg(1, qkv_w+49152,  qkvT+49152,  7, 384, 49152);
  seg(2, attn_w,       attnT,       7, 128, 16384);
  seg(3, attn_w+16384, attnT+16384, 7, 128, 16384);
  seg(4, fc1_w,        fc1T,        7, 512, 65536);
  seg(5, fc1_w+65536,  fc1T+65536,  7, 512, 65536);
  seg(6, fc2_w,        fc2T,        9, 128, 65536);
  seg(7, fc2_w+65536,  fc2T+65536,  9, 128, 65536);
  seg(8, h1_w,         h1T,         7, 128, 16384);
  seg(9, h2_w,         h2T,         7, 128, 16384);
  k_cvt_all<<<(base+255)/256,256,0,stream>>>(ca, base);
  k_cvtW3<<<576,256,0,stream>>>(proj_w1, BT3);
  k_fmapT<<<dim3(5,4,160), dim3(32,8), 0, stream>>>(fmap1, fT);

  // stage 1: transpose (cv -> d_out chunk 0, fp32) + cost filter + seeds
  k_transpose<<<dim3(5,4,1280), dim3(32,8), 0, stream>>>(cost_volume, outf);
  k_cost<<<6400,256,0,stream>>>(mlp_w1,mlp_b1, mlp_w2,mlp_b2, mlp_w3,mlp_b3, outf, seeds_i);

  // stage 2: context projection (conv3x3 via MFMA im2col)
  k_conv3<<<dim3(5,40,4),256,0,stream>>>(fT, BT3, tmp3);
  k_inorm<<<256,256,0,stream>>>(tmp3, musg);
  k_ctx<<<dim3(5,80,2),256,0,stream>>>(tmp3, musg, proj_w2, ctxT);

  // stage 3: embedding
  k_embed<<<6400,256,0,stream>>>(outf, ctxT, seeds_i, embed_w, embed_b, ctx_w, ctx_b, Xb);

  // stage 4: transformer (2 layers)
  for(int l=0;l<2;l++){
    k_qkv_attn<<<1600,256,0,stream>>>(Xb, qkvT + (size_t)l*49152, qkv_b + l*384, Ob);
    k_gemm128<1><<<1600,256,0,stream>>>(Ob, attnT + (size_t)l*16384, attn_b + l*128,
                                        Xb, ln1_g + l*128, ln1_b + l*128, X2b);
    k_mlp<<<1600,256,0,stream>>>(X2b, fc1T + (size_t)l*65536, fc1_b + l*512,
                                 fc2T + (size_t)l*65536, fc2_b + l*128,
                                 ln2_g + l*128, ln2_b + l*128, Xb);
  }

  // stage 5: final norm + head
  k_lnfinal<<<1600,256,0,stream>>>(Xb, normf_g, normf_b, Mb);
  k_gemm128<0><<<1600,256,0,stream>>>(Mb,  h1T, h1_b, nullptr, nullptr, nullptr, H1b);
  k_gemm128<0><<<1600,256,0,stream>>>(H1b, h2T, h2_b, nullptr, nullptr, nullptr, H2b);
  k_head3<<<400,256,0,stream>>>(H2b, h3_w, h3_b, seeds_i, outf);
}